// Round 1
// baseline (846.488 us; speedup 1.0000x reference)
//
#include <hip/hip_runtime.h>

#define S_LEN 2048
#define NH 16
#define HDIM 128
#define DMODEL 2048

typedef __attribute__((ext_vector_type(8))) short bf16x8;
typedef __attribute__((ext_vector_type(4))) float f32x4;

using gas_cvp = const __attribute__((address_space(1))) void*;
using las_vp  = __attribute__((address_space(3))) void*;

__device__ __forceinline__ unsigned short f2bf(float x) {
  unsigned int u = __builtin_bit_cast(unsigned int, x);
  u += 0x7FFFu + ((u >> 16) & 1u);
  return (unsigned short)(u >> 16);
}

// ---------- fp32 -> bf16 convert (vectorized) ----------
__global__ __launch_bounds__(256) void cvt_kernel(const float4* __restrict__ in,
                                                  ushort4* __restrict__ out, int n4) {
  int i = blockIdx.x * 256 + threadIdx.x;
  if (i < n4) {
    float4 v = in[i];
    ushort4 r;
    r.x = f2bf(v.x); r.y = f2bf(v.y); r.z = f2bf(v.z); r.w = f2bf(v.w);
    out[i] = r;
  }
}

// ---------- sin/cos table: sc[s][j] = {sin,cos}(s / 10000^(j/64)), j<64 ----------
__global__ __launch_bounds__(256) void sincos_kernel(float2* __restrict__ sc) {
  int i = blockIdx.x * 256 + threadIdx.x;   // S_LEN*64 threads
  int s = i >> 6, j = i & 63;
  float inv_ts = 1.0f / powf(10000.0f, (float)j * (1.0f / 64.0f));
  float ang = (float)s * inv_ts;
  sc[i] = make_float2(sinf(ang), cosf(ang));
}

// ---------- RoPE (+optional scale) fp32 -> bf16 ----------
__global__ __launch_bounds__(256) void rope_kernel(const float* __restrict__ X,
                                                   const float2* __restrict__ sc,
                                                   unsigned short* __restrict__ out,
                                                   float scale) {
  int i = blockIdx.x * 256 + threadIdx.x;   // [4096][16][64]
  int m = i >> 10;
  int r = i & 1023;
  int h = r >> 6, j = r & 63;
  int s = m & (S_LEN - 1);
  size_t base = (size_t)m * DMODEL + h * HDIM;
  float x1 = X[base + j], x2 = X[base + 64 + j];
  float2 cs = sc[s * 64 + j];
  out[base + j]      = f2bf((x1 * cs.y - x2 * cs.x) * scale);
  out[base + 64 + j] = f2bf((x2 * cs.y + x1 * cs.x) * scale);
}

// ---------- 2048x2048 transpose + convert: out[c][r] = bf16(in[r][c]) ----------
__global__ __launch_bounds__(256) void wtrans_kernel(const float* __restrict__ in,
                                                     unsigned short* __restrict__ out) {
  __shared__ float tile[64][65];
  int c0 = blockIdx.x * 64, r0 = blockIdx.y * 64;
  int tx = threadIdx.x & 63, ty = threadIdx.x >> 6;
#pragma unroll
  for (int i = 0; i < 16; i++) {
    int r = ty + i * 4;
    tile[r][tx] = in[(size_t)(r0 + r) * DMODEL + c0 + tx];
  }
  __syncthreads();
#pragma unroll
  for (int i = 0; i < 16; i++) {
    int c = ty + i * 4;
    out[(size_t)(c0 + c) * DMODEL + r0 + tx] = f2bf(tile[tx][c]);
  }
}

// ---------- V transpose: vf [B,S,H,HD] fp32 -> Vt [B,H,HD,S] bf16 ----------
__global__ __launch_bounds__(256) void vtrans_kernel(const float* __restrict__ vf,
                                                     unsigned short* __restrict__ Vt) {
  __shared__ float tile[64][65];
  int z = blockIdx.z; int b = z >> 4, h = z & 15;
  const float* I = vf + (size_t)b * S_LEN * DMODEL + h * HDIM;
  unsigned short* O = Vt + (size_t)z * HDIM * S_LEN;
  int s0 = blockIdx.y * 64, f0 = blockIdx.x * 64;
  int tx = threadIdx.x & 63, ty = threadIdx.x >> 6;
#pragma unroll
  for (int i = 0; i < 16; i++) {
    int r = ty + i * 4;
    tile[r][tx] = I[(size_t)(s0 + r) * DMODEL + f0 + tx];
  }
  __syncthreads();
#pragma unroll
  for (int i = 0; i < 16; i++) {
    int c = ty + i * 4;
    O[(size_t)(f0 + c) * S_LEN + s0 + tx] = f2bf(tile[tx][c]);
  }
}

// ---------- bf16 GEMM: C[m][n] = sum_k A[m][k] * Bt[n][k], fp32 out ----------
// m97-style: 128x128 tile, BK=32, 4 waves (2x2 of 64x64), global_load_lds w=16
__global__ __launch_bounds__(256) void gemm_bt_kernel(const unsigned short* __restrict__ A,
                                                      const unsigned short* __restrict__ Bt,
                                                      float* __restrict__ C,
                                                      int M, int N, int K) {
  __shared__ unsigned short As[128][32];
  __shared__ unsigned short Bs[128][32];
  int bn = blockIdx.x * 128, bm = blockIdx.y * 128;
  int tid = threadIdx.x, wave = tid >> 6, lane = tid & 63;
  int lr = lane & 15, lq = lane >> 4;
  int wm = (wave >> 1) * 64, wn = (wave & 1) * 64;
  f32x4 acc[4][4] = {};
  for (int k0 = 0; k0 < K; k0 += 32) {
    __syncthreads();
#pragma unroll
    for (int i = 0; i < 2; i++) {
      int boff = wave * 1024 + i * 4096;         // wave-uniform LDS byte base
      int off = boff + lane * 16;                // this lane's byte slot in tile
      int row = off >> 6;
      int cole = (off & 63) >> 1;
      __builtin_amdgcn_global_load_lds(
          (gas_cvp)(A + (size_t)(bm + row) * K + k0 + cole),
          (las_vp)((char*)&As[0][0] + boff), 16, 0, 0);
      __builtin_amdgcn_global_load_lds(
          (gas_cvp)(Bt + (size_t)(bn + row) * K + k0 + cole),
          (las_vp)((char*)&Bs[0][0] + boff), 16, 0, 0);
    }
    __syncthreads();
    bf16x8 a[4], b[4];
#pragma unroll
    for (int i = 0; i < 4; i++) a[i] = *(const bf16x8*)&As[wm + i * 16 + lr][lq * 8];
#pragma unroll
    for (int j = 0; j < 4; j++) b[j] = *(const bf16x8*)&Bs[wn + j * 16 + lr][lq * 8];
#pragma unroll
    for (int i = 0; i < 4; i++)
#pragma unroll
      for (int j = 0; j < 4; j++)
        acc[i][j] = __builtin_amdgcn_mfma_f32_16x16x32_bf16(a[i], b[j], acc[i][j], 0, 0, 0);
  }
#pragma unroll
  for (int i = 0; i < 4; i++)
#pragma unroll
    for (int j = 0; j < 4; j++) {
      int row0 = bm + wm + i * 16 + lq * 4;
      int col = bn + wn + j * 16 + lr;
#pragma unroll
      for (int r = 0; r < 4; r++)
        C[(size_t)(row0 + r) * N + col] = acc[i][j][r];
    }
}

// ---------- causal flash attention ----------
// grid (S/64, H, B); 4 independent waves per block, each owns 16 q-rows.
__global__ __launch_bounds__(256) void attn_kernel(const unsigned short* __restrict__ Qb,
                                                   const unsigned short* __restrict__ Kb,
                                                   const unsigned short* __restrict__ Vt,
                                                   unsigned short* __restrict__ ctx) {
  __shared__ unsigned short Plds[4][16][32];
  int b = blockIdx.z, h = blockIdx.y, q0 = blockIdx.x * 64;
  int tid = threadIdx.x, wave = tid >> 6, lane = tid & 63;
  int lr = lane & 15, lq = lane >> 4;
  int qw = q0 + wave * 16;
  const unsigned short* Qp = Qb + (size_t)b * S_LEN * DMODEL + (size_t)h * HDIM;
  const unsigned short* Kp = Kb + (size_t)b * S_LEN * DMODEL + (size_t)h * HDIM;
  const unsigned short* Vp = Vt + (size_t)(b * NH + h) * HDIM * S_LEN;

  bf16x8 qa[4];
#pragma unroll
  for (int kf = 0; kf < 4; kf++)
    qa[kf] = *(const bf16x8*)(Qp + (size_t)(qw + lr) * DMODEL + kf * 32 + lq * 8);

  f32x4 o[8] = {};
  float mrow[4] = {-1e30f, -1e30f, -1e30f, -1e30f};
  float lsum[4] = {0.f, 0.f, 0.f, 0.f};
  int kend = qw + 15;

  for (int k0 = 0; k0 <= kend; k0 += 32) {
    f32x4 sfrag[2] = {};
#pragma unroll
    for (int nf = 0; nf < 2; nf++)
#pragma unroll
      for (int kf = 0; kf < 4; kf++) {
        bf16x8 kb = *(const bf16x8*)(Kp + (size_t)(k0 + nf * 16 + lr) * DMODEL + kf * 32 + lq * 8);
        sfrag[nf] = __builtin_amdgcn_mfma_f32_16x16x32_bf16(qa[kf], kb, sfrag[nf], 0, 0, 0);
      }

    float alpha[4];
#pragma unroll
    for (int i2 = 0; i2 < 4; i2++) {
      int row = qw + lq * 4 + i2;
#pragma unroll
      for (int nf = 0; nf < 2; nf++) {
        int col = k0 + nf * 16 + lr;
        if (col > row) sfrag[nf][i2] = -1e30f;
      }
      float v = fmaxf(sfrag[0][i2], sfrag[1][i2]);
#pragma unroll
      for (int off = 1; off < 16; off <<= 1)
        v = fmaxf(v, __shfl_xor(v, off));
      float mn = fmaxf(mrow[i2], v);
      alpha[i2] = __expf(mrow[i2] - mn);
      mrow[i2] = mn;
    }

    f32x4 p2[2];
#pragma unroll
    for (int i2 = 0; i2 < 4; i2++) {
      p2[0][i2] = __expf(sfrag[0][i2] - mrow[i2]);
      p2[1][i2] = __expf(sfrag[1][i2] - mrow[i2]);
      float r = p2[0][i2] + p2[1][i2];
#pragma unroll
      for (int off = 1; off < 16; off <<= 1)
        r += __shfl_xor(r, off);
      lsum[i2] = lsum[i2] * alpha[i2] + r;
    }
#pragma unroll
    for (int ff = 0; ff < 8; ff++)
#pragma unroll
      for (int i2 = 0; i2 < 4; i2++)
        o[ff][i2] *= alpha[i2];

#pragma unroll
    for (int nf = 0; nf < 2; nf++)
#pragma unroll
      for (int i2 = 0; i2 < 4; i2++)
        Plds[wave][lq * 4 + i2][nf * 16 + lr] = f2bf(p2[nf][i2]);
    asm volatile("s_waitcnt lgkmcnt(0)" ::: "memory");
    bf16x8 pa = *(const bf16x8*)&Plds[wave][lr][lq * 8];

#pragma unroll
    for (int ff = 0; ff < 8; ff++) {
      bf16x8 vb = *(const bf16x8*)(Vp + (size_t)(ff * 16 + lr) * S_LEN + k0 + lq * 8);
      o[ff] = __builtin_amdgcn_mfma_f32_16x16x32_bf16(pa, vb, o[ff], 0, 0, 0);
    }
  }

#pragma unroll
  for (int i2 = 0; i2 < 4; i2++) {
    float inv = 1.0f / lsum[i2];
#pragma unroll
    for (int ff = 0; ff < 8; ff++)
      ctx[((size_t)b * S_LEN + qw + lq * 4 + i2) * DMODEL + h * HDIM + ff * 16 + lr] =
          f2bf(o[ff][i2] * inv);
  }
}

extern "C" void kernel_launch(void* const* d_in, const int* in_sizes, int n_in,
                              void* d_out, int out_size, void* d_ws, size_t ws_size,
                              hipStream_t stream) {
  const float* inq  = (const float*)d_in[0];
  const float* inkv = (const float*)d_in[1];
  const float* wq   = (const float*)d_in[2];
  const float* wk   = (const float*)d_in[3];
  const float* wv   = (const float*)d_in[4];
  const float* wo   = (const float*)d_in[5];
  float* out = (float*)d_out;

  char* ws = (char*)d_ws;
  const size_t MB = 1ull << 20;
  unsigned short* xq  = (unsigned short*)(ws);             // 16 MB
  unsigned short* xkv = (unsigned short*)(ws + 16 * MB);   // 16 MB
  unsigned short* wqt = (unsigned short*)(ws + 32 * MB);   // 8 MB
  unsigned short* wkt = (unsigned short*)(ws + 40 * MB);   // 8 MB
  unsigned short* wvt = (unsigned short*)(ws + 48 * MB);   // 8 MB
  unsigned short* wot = (unsigned short*)(ws + 56 * MB);   // 8 MB
  float2* sc          = (float2*)(ws + 64 * MB);           // 1 MB
  float* projf        = (float*)(ws + 66 * MB);            // 32 MB (reused q,k,v)
  unsigned short* Qb  = (unsigned short*)(ws + 98 * MB);   // 16 MB
  unsigned short* Kb  = (unsigned short*)(ws + 114 * MB);  // 16 MB
  unsigned short* Vt  = (unsigned short*)(ws + 130 * MB);  // 16 MB
  unsigned short* ctxb = (unsigned short*)(ws + 146 * MB); // 16 MB

  const int n4 = (2 * S_LEN * DMODEL) / 4;  // 2097152
  cvt_kernel<<<n4 / 256, 256, 0, stream>>>((const float4*)inq, (ushort4*)xq, n4);
  cvt_kernel<<<n4 / 256, 256, 0, stream>>>((const float4*)inkv, (ushort4*)xkv, n4);

  dim3 tg(32, 32);
  wtrans_kernel<<<tg, 256, 0, stream>>>(wq, wqt);
  wtrans_kernel<<<tg, 256, 0, stream>>>(wk, wkt);
  wtrans_kernel<<<tg, 256, 0, stream>>>(wv, wvt);
  wtrans_kernel<<<tg, 256, 0, stream>>>(wo, wot);

  sincos_kernel<<<(S_LEN * 64) / 256, 256, 0, stream>>>(sc);

  dim3 gg(16, 32);  // (N/128, M/128) for M=4096, N=2048
  const float qscale = 0.08838834764831845f;  // 1/sqrt(128)

  gemm_bt_kernel<<<gg, 256, 0, stream>>>(xq, wqt, projf, 4096, 2048, 2048);
  rope_kernel<<<16384, 256, 0, stream>>>(projf, sc, Qb, qscale);

  gemm_bt_kernel<<<gg, 256, 0, stream>>>(xkv, wkt, projf, 4096, 2048, 2048);
  rope_kernel<<<16384, 256, 0, stream>>>(projf, sc, Kb, 1.0f);

  gemm_bt_kernel<<<gg, 256, 0, stream>>>(xkv, wvt, projf, 4096, 2048, 2048);
  vtrans_kernel<<<dim3(2, 32, 32), 256, 0, stream>>>(projf, Vt);

  attn_kernel<<<dim3(S_LEN / 64, NH, 2), 256, 0, stream>>>(Qb, Kb, Vt, ctxb);

  gemm_bt_kernel<<<gg, 256, 0, stream>>>(ctxb, wot, out, 4096, 2048, 2048);
}

// Round 2
// 472.932 us; speedup vs baseline: 1.7899x; 1.7899x over previous
//
#include <hip/hip_runtime.h>

#define S_LEN 2048
#define NH 16
#define HDIM 128
#define DMODEL 2048

typedef __attribute__((ext_vector_type(8))) short bf16x8;
typedef __attribute__((ext_vector_type(4))) float f32x4;

using gas_cvp = const __attribute__((address_space(1))) void*;
using las_vp  = __attribute__((address_space(3))) void*;

__device__ __forceinline__ unsigned short f2bf(float x) {
  unsigned int u = __builtin_bit_cast(unsigned int, x);
  u += 0x7FFFu + ((u >> 16) & 1u);
  return (unsigned short)(u >> 16);
}

// ---------- fp32 -> bf16 convert (vectorized) ----------
__global__ __launch_bounds__(256) void cvt_kernel(const float4* __restrict__ in,
                                                  ushort4* __restrict__ out, int n4) {
  int i = blockIdx.x * 256 + threadIdx.x;
  if (i < n4) {
    float4 v = in[i];
    ushort4 r;
    r.x = f2bf(v.x); r.y = f2bf(v.y); r.z = f2bf(v.z); r.w = f2bf(v.w);
    out[i] = r;
  }
}

// ---------- sin/cos table ----------
__global__ __launch_bounds__(256) void sincos_kernel(float2* __restrict__ sc) {
  int i = blockIdx.x * 256 + threadIdx.x;   // S_LEN*64 threads
  int s = i >> 6, j = i & 63;
  float inv_ts = 1.0f / powf(10000.0f, (float)j * (1.0f / 64.0f));
  float ang = (float)s * inv_ts;
  sc[i] = make_float2(sinf(ang), cosf(ang));
}

// ---------- RoPE (+optional scale) fp32 -> bf16 ----------
__global__ __launch_bounds__(256) void rope_kernel(const float* __restrict__ X,
                                                   const float2* __restrict__ sc,
                                                   unsigned short* __restrict__ out,
                                                   float scale) {
  int i = blockIdx.x * 256 + threadIdx.x;   // [4096][16][64]
  int m = i >> 10;
  int r = i & 1023;
  int h = r >> 6, j = r & 63;
  int s = m & (S_LEN - 1);
  size_t base = (size_t)m * DMODEL + h * HDIM;
  float x1 = X[base + j], x2 = X[base + 64 + j];
  float2 cs = sc[s * 64 + j];
  out[base + j]      = f2bf((x1 * cs.y - x2 * cs.x) * scale);
  out[base + 64 + j] = f2bf((x2 * cs.y + x1 * cs.x) * scale);
}

// ---------- 2048x2048 transpose + convert ----------
__global__ __launch_bounds__(256) void wtrans_kernel(const float* __restrict__ in,
                                                     unsigned short* __restrict__ out) {
  __shared__ float tile[64][65];
  int c0 = blockIdx.x * 64, r0 = blockIdx.y * 64;
  int tx = threadIdx.x & 63, ty = threadIdx.x >> 6;
#pragma unroll
  for (int i = 0; i < 16; i++) {
    int r = ty + i * 4;
    tile[r][tx] = in[(size_t)(r0 + r) * DMODEL + c0 + tx];
  }
  __syncthreads();
#pragma unroll
  for (int i = 0; i < 16; i++) {
    int c = ty + i * 4;
    out[(size_t)(c0 + c) * DMODEL + r0 + tx] = f2bf(tile[tx][c]);
  }
}

// ---------- V transpose: vf [B,S,H,HD] fp32 -> Vt [B,H,HD,S] bf16 ----------
__global__ __launch_bounds__(256) void vtrans_kernel(const float* __restrict__ vf,
                                                     unsigned short* __restrict__ Vt) {
  __shared__ float tile[64][65];
  int z = blockIdx.z; int b = z >> 4, h = z & 15;
  const float* I = vf + (size_t)b * S_LEN * DMODEL + h * HDIM;
  unsigned short* O = Vt + (size_t)z * HDIM * S_LEN;
  int s0 = blockIdx.y * 64, f0 = blockIdx.x * 64;
  int tx = threadIdx.x & 63, ty = threadIdx.x >> 6;
#pragma unroll
  for (int i = 0; i < 16; i++) {
    int r = ty + i * 4;
    tile[r][tx] = I[(size_t)(s0 + r) * DMODEL + f0 + tx];
  }
  __syncthreads();
#pragma unroll
  for (int i = 0; i < 16; i++) {
    int c = ty + i * 4;
    O[(size_t)(f0 + c) * S_LEN + s0 + tx] = f2bf(tile[tx][c]);
  }
}

// ---------- bf16 GEMM: C[m][n] = sum_k A[m][k] * Bt[n][k], fp32 out ----------
__global__ __launch_bounds__(256) void gemm_bt_kernel(const unsigned short* __restrict__ A,
                                                      const unsigned short* __restrict__ Bt,
                                                      float* __restrict__ C,
                                                      int M, int N, int K) {
  __shared__ unsigned short As[128][32];
  __shared__ unsigned short Bs[128][32];
  int bn = blockIdx.x * 128, bm = blockIdx.y * 128;
  int tid = threadIdx.x, wave = tid >> 6, lane = tid & 63;
  int lr = lane & 15, lq = lane >> 4;
  int wm = (wave >> 1) * 64, wn = (wave & 1) * 64;
  f32x4 acc[4][4] = {};
  for (int k0 = 0; k0 < K; k0 += 32) {
    __syncthreads();
#pragma unroll
    for (int i = 0; i < 2; i++) {
      int boff = wave * 1024 + i * 4096;
      int off = boff + lane * 16;
      int row = off >> 6;
      int cole = (off & 63) >> 1;
      __builtin_amdgcn_global_load_lds(
          (gas_cvp)(A + (size_t)(bm + row) * K + k0 + cole),
          (las_vp)((char*)&As[0][0] + boff), 16, 0, 0);
      __builtin_amdgcn_global_load_lds(
          (gas_cvp)(Bt + (size_t)(bn + row) * K + k0 + cole),
          (las_vp)((char*)&Bs[0][0] + boff), 16, 0, 0);
    }
    __syncthreads();
    bf16x8 a[4], b[4];
#pragma unroll
    for (int i = 0; i < 4; i++) a[i] = *(const bf16x8*)&As[wm + i * 16 + lr][lq * 8];
#pragma unroll
    for (int j = 0; j < 4; j++) b[j] = *(const bf16x8*)&Bs[wn + j * 16 + lr][lq * 8];
#pragma unroll
    for (int i = 0; i < 4; i++)
#pragma unroll
      for (int j = 0; j < 4; j++)
        acc[i][j] = __builtin_amdgcn_mfma_f32_16x16x32_bf16(a[i], b[j], acc[i][j], 0, 0, 0);
  }
#pragma unroll
  for (int i = 0; i < 4; i++)
#pragma unroll
    for (int j = 0; j < 4; j++) {
      int row0 = bm + wm + i * 16 + lq * 4;
      int col = bn + wn + j * 16 + lr;
#pragma unroll
      for (int r = 0; r < 4; r++)
        C[(size_t)(row0 + r) * N + col] = acc[i][j][r];
    }
}

// ---------- causal flash attention, LDS-staged double-buffered KV ----------
// grid (S/128, H, B); 4 waves/block, each owns 32 q-rows (2 m-frags).
// KV tile = 64 rows. K tile [64][128] bf16 (16KB), V^T tile [128][64] (16KB),
// double-buffered (64KB). XOR-swizzle byte^=((row&7)<<4) applied on the
// global SOURCE side of global_load_lds (dest stays linear) and on every
// LDS read (same involution). P reuses the K region of the current buffer
// after the mid-iteration barrier.
__global__ __launch_bounds__(256, 2) void attn_kernel(const unsigned short* __restrict__ Qb,
                                                      const unsigned short* __restrict__ Kb,
                                                      const unsigned short* __restrict__ Vt,
                                                      unsigned short* __restrict__ ctx) {
  __shared__ char lds[65536];
  int b = blockIdx.z, h = blockIdx.y;
  int q0 = blockIdx.x * 128;
  int tid = threadIdx.x, wave = tid >> 6, lane = tid & 63;
  int lr = lane & 15, lq = lane >> 4;
  int qw = q0 + wave * 32;
  const unsigned short* Qp = Qb + (size_t)b * S_LEN * DMODEL + (size_t)h * HDIM;
  const unsigned short* Kp = Kb + (size_t)b * S_LEN * DMODEL + (size_t)h * HDIM;
  const unsigned short* Vp = Vt + (size_t)(b * NH + h) * HDIM * S_LEN;

  // Q fragments (stay in registers for the whole kernel)
  bf16x8 qa[2][4];
#pragma unroll
  for (int mi = 0; mi < 2; mi++)
#pragma unroll
    for (int kf = 0; kf < 4; kf++)
      qa[mi][kf] = *(const bf16x8*)(Qp + (size_t)(qw + mi * 16 + lr) * DMODEL + kf * 32 + lq * 8);

  f32x4 o[2][8] = {};
  float mrow[2][4], lsum[2][4];
#pragma unroll
  for (int mi = 0; mi < 2; mi++)
#pragma unroll
    for (int i2 = 0; i2 < 4; i2++) { mrow[mi][i2] = -1e30f; lsum[mi][i2] = 0.f; }

  const int nt = 2 * blockIdx.x + 2;

  auto STAGE = [&](int tt, int bsel) {
    int kk0 = tt * 64;
#pragma unroll
    for (int i = 0; i < 4; i++) {            // K tile: [64][128] bf16, rows 256B
      int o_ = wave * 4096 + i * 1024 + lane * 16;
      int row = o_ >> 8, colb = o_ & 255;
      int sc_ = colb ^ ((row & 7) << 4);
      __builtin_amdgcn_global_load_lds(
          (gas_cvp)(Kp + (size_t)(kk0 + row) * DMODEL + (sc_ >> 1)),
          (las_vp)(lds + bsel * 32768 + wave * 4096 + i * 1024), 16, 0, 0);
    }
#pragma unroll
    for (int i = 0; i < 4; i++) {            // V^T tile: [128][64] bf16, rows 128B
      int o_ = wave * 4096 + i * 1024 + lane * 16;
      int row = o_ >> 7, colb = o_ & 127;
      int sc_ = colb ^ ((row & 7) << 4);
      __builtin_amdgcn_global_load_lds(
          (gas_cvp)(Vp + (size_t)row * S_LEN + kk0 + (sc_ >> 1)),
          (las_vp)(lds + bsel * 32768 + 16384 + wave * 4096 + i * 1024), 16, 0, 0);
    }
  };

  STAGE(0, 0);
  __syncthreads();

  for (int t = 0; t < nt; t++) {
    int cur = t & 1;
    int k0 = t * 64;
    if (t + 1 < nt) STAGE(t + 1, cur ^ 1);

    bool active = (k0 <= qw + 31);
    float p[2][4][4];
    if (active) {
      const char* kbb = lds + cur * 32768;
      f32x4 sf[2][4] = {};
#pragma unroll
      for (int kf = 0; kf < 4; kf++) {
        bf16x8 kbf[4];
#pragma unroll
        for (int nf = 0; nf < 4; nf++) {
          int row = nf * 16 + lr;
          int colb = kf * 64 + lq * 16;
          kbf[nf] = *(const bf16x8*)(kbb + row * 256 + (colb ^ ((row & 7) << 4)));
        }
#pragma unroll
        for (int nf = 0; nf < 4; nf++)
#pragma unroll
          for (int mi = 0; mi < 2; mi++)
            sf[mi][nf] = __builtin_amdgcn_mfma_f32_16x16x32_bf16(qa[mi][kf], kbf[nf], sf[mi][nf], 0, 0, 0);
      }

      bool needmask = (k0 + 63 > qw);
#pragma unroll
      for (int mi = 0; mi < 2; mi++)
#pragma unroll
        for (int i2 = 0; i2 < 4; i2++) {
          int row = qw + mi * 16 + lq * 4 + i2;
          if (needmask) {
#pragma unroll
            for (int nf = 0; nf < 4; nf++) {
              int col = k0 + nf * 16 + lr;
              if (col > row) sf[mi][nf][i2] = -1e30f;
            }
          }
          float v = fmaxf(fmaxf(sf[mi][0][i2], sf[mi][1][i2]),
                          fmaxf(sf[mi][2][i2], sf[mi][3][i2]));
#pragma unroll
          for (int off = 1; off < 16; off <<= 1)
            v = fmaxf(v, __shfl_xor(v, off));
          float mn = fmaxf(mrow[mi][i2], v);
          float al = __expf(mrow[mi][i2] - mn);
          mrow[mi][i2] = mn;
          float r = 0.f;
#pragma unroll
          for (int nf = 0; nf < 4; nf++) {
            p[mi][nf][i2] = __expf(sf[mi][nf][i2] - mn);
            r += p[mi][nf][i2];
          }
#pragma unroll
          for (int off = 1; off < 16; off <<= 1)
            r += __shfl_xor(r, off);
          lsum[mi][i2] = lsum[mi][i2] * al + r;
#pragma unroll
          for (int ff = 0; ff < 8; ff++)
            o[mi][ff][i2] *= al;
        }
    }

    __syncthreads();   // all waves done reading K[cur]; staged loads drained

    if (active) {
      char* pb = lds + cur * 32768 + wave * 4096;  // P: [32][64] bf16 per wave
#pragma unroll
      for (int mi = 0; mi < 2; mi++)
#pragma unroll
        for (int nf = 0; nf < 4; nf++)
#pragma unroll
          for (int i2 = 0; i2 < 4; i2++) {
            int row = mi * 16 + lq * 4 + i2;
            int colb = (nf * 16 + lr) * 2;
            *(unsigned short*)(pb + row * 128 + (colb ^ ((row & 7) << 4))) = f2bf(p[mi][nf][i2]);
          }
      const char* vbb = lds + cur * 32768 + 16384;
#pragma unroll
      for (int kk = 0; kk < 2; kk++) {
        bf16x8 pa[2];
#pragma unroll
        for (int mi = 0; mi < 2; mi++) {
          int row = mi * 16 + lr;
          int colb = kk * 64 + lq * 16;
          pa[mi] = *(const bf16x8*)(pb + row * 128 + (colb ^ ((row & 7) << 4)));
        }
#pragma unroll
        for (int ff = 0; ff < 8; ff++) {
          int row = ff * 16 + lr;
          int colb = kk * 64 + lq * 16;
          bf16x8 vb = *(const bf16x8*)(vbb + row * 128 + (colb ^ ((row & 7) << 4)));
#pragma unroll
          for (int mi = 0; mi < 2; mi++)
            o[mi][ff] = __builtin_amdgcn_mfma_f32_16x16x32_bf16(pa[mi], vb, o[mi][ff], 0, 0, 0);
        }
      }
    }

    __syncthreads();   // all waves done with buf[cur] (V + P regions)
  }

#pragma unroll
  for (int mi = 0; mi < 2; mi++)
#pragma unroll
    for (int i2 = 0; i2 < 4; i2++) {
      float inv = 1.0f / lsum[mi][i2];
      size_t rb = ((size_t)b * S_LEN + qw + mi * 16 + lq * 4 + i2) * DMODEL + h * HDIM;
#pragma unroll
      for (int ff = 0; ff < 8; ff++)
        ctx[rb + ff * 16 + lr] = f2bf(o[mi][ff][i2] * inv);
    }
}

extern "C" void kernel_launch(void* const* d_in, const int* in_sizes, int n_in,
                              void* d_out, int out_size, void* d_ws, size_t ws_size,
                              hipStream_t stream) {
  const float* inq  = (const float*)d_in[0];
  const float* inkv = (const float*)d_in[1];
  const float* wq   = (const float*)d_in[2];
  const float* wk   = (const float*)d_in[3];
  const float* wv   = (const float*)d_in[4];
  const float* wo   = (const float*)d_in[5];
  float* out = (float*)d_out;

  char* ws = (char*)d_ws;
  const size_t MB = 1ull << 20;
  unsigned short* xq  = (unsigned short*)(ws);             // 16 MB
  unsigned short* xkv = (unsigned short*)(ws + 16 * MB);   // 16 MB
  unsigned short* wqt = (unsigned short*)(ws + 32 * MB);   // 8 MB
  unsigned short* wkt = (unsigned short*)(ws + 40 * MB);   // 8 MB
  unsigned short* wvt = (unsigned short*)(ws + 48 * MB);   // 8 MB
  unsigned short* wot = (unsigned short*)(ws + 56 * MB);   // 8 MB
  float2* sc          = (float2*)(ws + 64 * MB);           // 1 MB
  float* projf        = (float*)(ws + 66 * MB);            // 32 MB (reused q,k,v)
  unsigned short* Qb  = (unsigned short*)(ws + 98 * MB);   // 16 MB
  unsigned short* Kb  = (unsigned short*)(ws + 114 * MB);  // 16 MB
  unsigned short* Vt  = (unsigned short*)(ws + 130 * MB);  // 16 MB
  unsigned short* ctxb = (unsigned short*)(ws + 146 * MB); // 16 MB

  const int n4 = (2 * S_LEN * DMODEL) / 4;
  cvt_kernel<<<n4 / 256, 256, 0, stream>>>((const float4*)inq, (ushort4*)xq, n4);
  cvt_kernel<<<n4 / 256, 256, 0, stream>>>((const float4*)inkv, (ushort4*)xkv, n4);

  dim3 tg(32, 32);
  wtrans_kernel<<<tg, 256, 0, stream>>>(wq, wqt);
  wtrans_kernel<<<tg, 256, 0, stream>>>(wk, wkt);
  wtrans_kernel<<<tg, 256, 0, stream>>>(wv, wvt);
  wtrans_kernel<<<tg, 256, 0, stream>>>(wo, wot);

  sincos_kernel<<<(S_LEN * 64) / 256, 256, 0, stream>>>(sc);

  dim3 gg(16, 32);  // (N/128, M/128) for M=4096, N=2048
  const float qscale = 0.08838834764831845f;  // 1/sqrt(128)

  gemm_bt_kernel<<<gg, 256, 0, stream>>>(xq, wqt, projf, 4096, 2048, 2048);
  rope_kernel<<<16384, 256, 0, stream>>>(projf, sc, Qb, qscale);

  gemm_bt_kernel<<<gg, 256, 0, stream>>>(xkv, wkt, projf, 4096, 2048, 2048);
  rope_kernel<<<16384, 256, 0, stream>>>(projf, sc, Kb, 1.0f);

  gemm_bt_kernel<<<gg, 256, 0, stream>>>(xkv, wvt, projf, 4096, 2048, 2048);
  vtrans_kernel<<<dim3(2, 32, 32), 256, 0, stream>>>(projf, Vt);

  attn_kernel<<<dim3(S_LEN / 128, NH, 2), 256, 0, stream>>>(Qb, Kb, Vt, ctxb);

  gemm_bt_kernel<<<gg, 256, 0, stream>>>(ctxb, wot, out, 4096, 2048, 2048);
}

// Round 3
// 379.316 us; speedup vs baseline: 2.2316x; 1.2468x over previous
//
#include <hip/hip_runtime.h>

#define S_LEN 2048
#define NH 16
#define HDIM 128
#define DMODEL 2048

typedef __attribute__((ext_vector_type(8))) short bf16x8;
typedef __attribute__((ext_vector_type(4))) float f32x4;

using gas_cvp = const __attribute__((address_space(1))) void*;
using las_vp  = __attribute__((address_space(3))) void*;

__device__ __forceinline__ unsigned short f2bf(float x) {
  unsigned int u = __builtin_bit_cast(unsigned int, x);
  u += 0x7FFFu + ((u >> 16) & 1u);
  return (unsigned short)(u >> 16);
}
__device__ __forceinline__ float bf2f(unsigned short u) {
  unsigned int x = ((unsigned int)u) << 16;
  return __builtin_bit_cast(float, x);
}

// ---------- fp32 -> bf16 convert ----------
__global__ __launch_bounds__(256) void cvt_kernel(const float4* __restrict__ in,
                                                  ushort4* __restrict__ out, int n4) {
  int i = blockIdx.x * 256 + threadIdx.x;
  if (i < n4) {
    float4 v = in[i];
    ushort4 r;
    r.x = f2bf(v.x); r.y = f2bf(v.y); r.z = f2bf(v.z); r.w = f2bf(v.w);
    out[i] = r;
  }
}

// ---------- sin/cos table ----------
__global__ __launch_bounds__(256) void sincos_kernel(float2* __restrict__ sc) {
  int i = blockIdx.x * 256 + threadIdx.x;
  int s = i >> 6, j = i & 63;
  float inv_ts = 1.0f / powf(10000.0f, (float)j * (1.0f / 64.0f));
  float ang = (float)s * inv_ts;
  sc[i] = make_float2(sinf(ang), cosf(ang));
}

// ---------- RoPE (+scale), bf16 in -> bf16 out ----------
__global__ __launch_bounds__(256) void rope_kernel(const unsigned short* __restrict__ X,
                                                   const float2* __restrict__ sc,
                                                   unsigned short* __restrict__ out,
                                                   float scale) {
  int i = blockIdx.x * 256 + threadIdx.x;   // [4096][16][64]
  int m = i >> 10;
  int r = i & 1023;
  int h = r >> 6, j = r & 63;
  int s = m & (S_LEN - 1);
  size_t base = (size_t)m * DMODEL + h * HDIM;
  float x1 = bf2f(X[base + j]), x2 = bf2f(X[base + 64 + j]);
  float2 cs = sc[s * 64 + j];
  out[base + j]      = f2bf((x1 * cs.y - x2 * cs.x) * scale);
  out[base + 64 + j] = f2bf((x2 * cs.y + x1 * cs.x) * scale);
}

// ---------- 2048x2048 weight transpose + convert (fp32 in, bf16 out) ----------
__global__ __launch_bounds__(256) void wtrans_kernel(const float* __restrict__ in,
                                                     unsigned short* __restrict__ out) {
  __shared__ float tile[64][65];
  int c0 = blockIdx.x * 64, r0 = blockIdx.y * 64;
  int tx = threadIdx.x & 63, ty = threadIdx.x >> 6;
#pragma unroll
  for (int i = 0; i < 16; i++) {
    int r = ty + i * 4;
    tile[r][tx] = in[(size_t)(r0 + r) * DMODEL + c0 + tx];
  }
  __syncthreads();
#pragma unroll
  for (int i = 0; i < 16; i++) {
    int c = ty + i * 4;
    out[(size_t)(c0 + c) * DMODEL + r0 + tx] = f2bf(tile[tx][c]);
  }
}

// ---------- V transpose: [B,S,H,HD] bf16 -> [B,H,HD,S] bf16 ----------
__global__ __launch_bounds__(256) void vtrans_kernel(const unsigned short* __restrict__ vf,
                                                     unsigned short* __restrict__ Vt) {
  __shared__ unsigned short tile[64][65];
  int z = blockIdx.z; int b = z >> 4, h = z & 15;
  const unsigned short* I = vf + (size_t)b * S_LEN * DMODEL + h * HDIM;
  unsigned short* O = Vt + (size_t)z * HDIM * S_LEN;
  int s0 = blockIdx.y * 64, f0 = blockIdx.x * 64;
  int tx = threadIdx.x & 63, ty = threadIdx.x >> 6;
#pragma unroll
  for (int i = 0; i < 16; i++) {
    int r = ty + i * 4;
    tile[r][tx] = I[(size_t)(s0 + r) * DMODEL + f0 + tx];
  }
  __syncthreads();
#pragma unroll
  for (int i = 0; i < 16; i++) {
    int c = ty + i * 4;
    O[(size_t)(f0 + c) * S_LEN + s0 + tx] = tile[tx][c];
  }
}

// ---------- 8-phase 256x256 bf16 GEMM (m201 template) ----------
// C[m][n] = sum_k A[m][k]*Bt[n][k].  M=4096, N=2048, K=2048 fixed.
// 512 thr (8 waves, 2M x 4N), BK=64, LDS 128KB: per-buf {A half0,A half1,B half0,B half1} @16KB.
// XOR swizzle byte^=((row&7)<<4): linear LDS dest + pre-swizzled global source (rule #21).
template <bool BF16OUT>
__global__ __launch_bounds__(512) void gemm8_kernel(
    const unsigned short* __restrict__ Aq,
    const unsigned short* __restrict__ Akv,
    const unsigned short* __restrict__ W,   // [z][N][K]
    void* __restrict__ Cb) {                // [z][M][N]
  constexpr int M = 4096, N = 2048, K = 2048, NT = K / 64;
  __shared__ char lds[131072];
  int z = blockIdx.z;
  const unsigned short* A = (z == 0) ? Aq : Akv;
  const unsigned short* Bt = W + (size_t)z * N * K;
  int bm = blockIdx.y * 256, bn = blockIdx.x * 256;
  int tid = threadIdx.x, wave = tid >> 6, lane = tid & 63;
  int lr = lane & 15, lq = lane >> 4;
  int wr = wave >> 2, wc = wave & 3;

  // stage one 16KB half-tile: ht 0=Ah0 1=Ah1 2=Bh0 3=Bh1
  auto STAGE_HALF = [&](int t, int buf, int ht) {
    int tt = t & (NT - 1);
    int k0 = tt * 64;
    const unsigned short* src = (ht < 2) ? A : Bt;
    int rbase = (ht < 2) ? bm : bn;
    int half = ht & 1;
    char* dst0 = lds + buf * 65536 + ht * 16384;
#pragma unroll
    for (int i = 0; i < 2; i++) {
      int o = i * 8192 + wave * 1024 + lane * 16;
      int row = o >> 7;
      int colb = o & 127;
      int sc = colb ^ ((row & 7) << 4);
      __builtin_amdgcn_global_load_lds(
          (gas_cvp)(src + (size_t)(rbase + half * 128 + row) * K + k0 + (sc >> 1)),
          (las_vp)(dst0 + i * 8192 + wave * 1024), 16, 0, 0);
    }
  };
  auto LDA = [&](int buf, int m, int kk) -> bf16x8 {
    int row = m * 16 + lr;
    int byt = row * 128 + (((kk * 4 + lq) ^ (row & 7)) << 4);
    return *(const bf16x8*)(lds + buf * 65536 + wr * 16384 + byt);
  };
  auto LDB = [&](int buf, int n, int kk) -> bf16x8 {
    int row = wc * 64 + n * 16 + lr;
    int half = row >> 7, r = row & 127;
    int byt = r * 128 + (((kk * 4 + lq) ^ (r & 7)) << 4);
    return *(const bf16x8*)(lds + buf * 65536 + 32768 + half * 16384 + byt);
  };

  f32x4 acc[8][4] = {};
  bf16x8 aA[4][2], bB[4][2];

  auto MFMA_Q = [&](int mg, int ng) {
#pragma unroll
    for (int kk = 0; kk < 2; kk++)
#pragma unroll
      for (int mm = 0; mm < 4; mm++)
#pragma unroll
        for (int nn = 0; nn < 2; nn++)
          acc[mg * 4 + mm][ng * 2 + nn] = __builtin_amdgcn_mfma_f32_16x16x32_bf16(
              aA[mm][kk], bB[ng * 2 + nn][kk], acc[mg * 4 + mm][ng * 2 + nn], 0, 0, 0);
  };
  auto PHASE_SYNC = [&]() {
    __builtin_amdgcn_s_barrier();
    asm volatile("s_waitcnt lgkmcnt(0)" ::: "memory");
    __builtin_amdgcn_sched_barrier(0);
    __builtin_amdgcn_s_setprio(1);
  };
  auto PHASE_END = [&]() {
    __builtin_amdgcn_s_setprio(0);
    __builtin_amdgcn_s_barrier();
  };

  // prologue: T0 full (buf0) + B halves of T1 (buf1) = 12 loads
  STAGE_HALF(0, 0, 0); STAGE_HALF(0, 0, 1); STAGE_HALF(0, 0, 2); STAGE_HALF(0, 0, 3);
  STAGE_HALF(1, 1, 2); STAGE_HALF(1, 1, 3);
  asm volatile("s_waitcnt vmcnt(4)" ::: "memory");   // T0's 8 loads drained
  __builtin_amdgcn_sched_barrier(0);
  __builtin_amdgcn_s_barrier();

  for (int i = 0; i < NT / 2; i++) {
    int T0 = 2 * i, T1 = 2 * i + 1;
    // ph1: T0.q0  (reads buf0 A m0-3, B n0-1; stage A1h0 of T1)
#pragma unroll
    for (int kk = 0; kk < 2; kk++) {
#pragma unroll
      for (int mm = 0; mm < 4; mm++) aA[mm][kk] = LDA(0, mm, kk);
#pragma unroll
      for (int nn = 0; nn < 2; nn++) bB[nn][kk] = LDB(0, nn, kk);
    }
    STAGE_HALF(T1, 1, 0);
    PHASE_SYNC(); MFMA_Q(0, 0); PHASE_END();

    // ph2: T0.q1
#pragma unroll
    for (int kk = 0; kk < 2; kk++)
#pragma unroll
      for (int nn = 0; nn < 2; nn++) bB[2 + nn][kk] = LDB(0, 2 + nn, kk);
    STAGE_HALF(T1, 1, 1);
    PHASE_SYNC(); MFMA_Q(0, 1); PHASE_END();

    // ph3: T0.q2
#pragma unroll
    for (int kk = 0; kk < 2; kk++)
#pragma unroll
      for (int mm = 0; mm < 4; mm++) aA[mm][kk] = LDA(0, 4 + mm, kk);
    STAGE_HALF(T0 + 2, 0, 2);
    PHASE_SYNC(); MFMA_Q(1, 0); PHASE_END();

    // ph4: T0.q3  (+ vmcnt(4): T1's A+B all drained; newest-4 = ph3,ph4 stages)
    STAGE_HALF(T0 + 2, 0, 3);
    asm volatile("s_waitcnt vmcnt(4)" ::: "memory");
    __builtin_amdgcn_sched_barrier(0);
    PHASE_SYNC(); MFMA_Q(1, 1); PHASE_END();

    // ph5: T1.q0
#pragma unroll
    for (int kk = 0; kk < 2; kk++) {
#pragma unroll
      for (int mm = 0; mm < 4; mm++) aA[mm][kk] = LDA(1, mm, kk);
#pragma unroll
      for (int nn = 0; nn < 2; nn++) bB[nn][kk] = LDB(1, nn, kk);
    }
    STAGE_HALF(T0 + 2, 0, 0);
    PHASE_SYNC(); MFMA_Q(0, 0); PHASE_END();

    // ph6: T1.q1
#pragma unroll
    for (int kk = 0; kk < 2; kk++)
#pragma unroll
      for (int nn = 0; nn < 2; nn++) bB[2 + nn][kk] = LDB(1, 2 + nn, kk);
    STAGE_HALF(T0 + 2, 0, 1);
    PHASE_SYNC(); MFMA_Q(0, 1); PHASE_END();

    // ph7: T1.q2
#pragma unroll
    for (int kk = 0; kk < 2; kk++)
#pragma unroll
      for (int mm = 0; mm < 4; mm++) aA[mm][kk] = LDA(1, 4 + mm, kk);
    STAGE_HALF(T1 + 2, 1, 2);
    PHASE_SYNC(); MFMA_Q(1, 0); PHASE_END();

    // ph8: T1.q3  (+ vmcnt(4): T0+2's A+B drained; newest-4 = ph7,ph8 stages)
    STAGE_HALF(T1 + 2, 1, 3);
    asm volatile("s_waitcnt vmcnt(4)" ::: "memory");
    __builtin_amdgcn_sched_barrier(0);
    PHASE_SYNC(); MFMA_Q(1, 1); PHASE_END();
  }
  asm volatile("s_waitcnt vmcnt(0)" ::: "memory");

  // epilogue
#pragma unroll
  for (int m = 0; m < 8; m++)
#pragma unroll
    for (int n = 0; n < 4; n++) {
      int row0 = bm + wr * 128 + m * 16 + lq * 4;
      int col = bn + wc * 64 + n * 16 + lr;
      if (BF16OUT) {
        unsigned short* C = (unsigned short*)Cb + (size_t)z * M * N;
#pragma unroll
        for (int r = 0; r < 4; r++)
          C[(size_t)(row0 + r) * N + col] = f2bf(acc[m][n][r]);
      } else {
        float* C = (float*)Cb + (size_t)z * M * N;
#pragma unroll
        for (int r = 0; r < 4; r++)
          C[(size_t)(row0 + r) * N + col] = acc[m][n][r];
      }
    }
}

// ---------- causal flash attention, paired q-tiles for load balance ----------
// grid (8, H, B); 512 thr. Waves 0-3 own q-tile j, waves 4-7 own q-tile 15-j
// (constant compute per block). KV tile 64 rows dbuf (2x32KB) + 32KB P region.
__global__ __launch_bounds__(512, 1) void attn_kernel(const unsigned short* __restrict__ Qb,
                                                      const unsigned short* __restrict__ Kb,
                                                      const unsigned short* __restrict__ Vt,
                                                      unsigned short* __restrict__ ctx) {
  __shared__ char lds[98304];
  int b = blockIdx.z, h = blockIdx.y;
  int tid = threadIdx.x, wave = tid >> 6, lane = tid & 63;
  int lr = lane & 15, lq = lane >> 4;
  int grp = wave >> 2, wsub = wave & 3;
  int jlo = blockIdx.x;                       // 0..7
  int qtile = grp ? (15 - jlo) : jlo;
  int qw = qtile * 128 + wsub * 32;
  int nt = 2 * (15 - jlo) + 2;                // trips for the heavy tile

  const unsigned short* Qp = Qb + (size_t)b * S_LEN * DMODEL + (size_t)h * HDIM;
  const unsigned short* Kp = Kb + (size_t)b * S_LEN * DMODEL + (size_t)h * HDIM;
  const unsigned short* Vp = Vt + (size_t)(b * NH + h) * HDIM * S_LEN;

  bf16x8 qa[2][4];
#pragma unroll
  for (int mi = 0; mi < 2; mi++)
#pragma unroll
    for (int kf = 0; kf < 4; kf++)
      qa[mi][kf] = *(const bf16x8*)(Qp + (size_t)(qw + mi * 16 + lr) * DMODEL + kf * 32 + lq * 8);

  f32x4 o[2][8] = {};
  float mrow[2][4], lsum[2][4];
#pragma unroll
  for (int mi = 0; mi < 2; mi++)
#pragma unroll
    for (int i2 = 0; i2 < 4; i2++) { mrow[mi][i2] = -1e30f; lsum[mi][i2] = 0.f; }

  auto STAGE = [&](int tt, int bsel) {
    int kk0 = tt * 64;
#pragma unroll
    for (int i = 0; i < 2; i++) {             // K tile [64][128] bf16, 16KB
      int o_ = wave * 2048 + i * 1024 + lane * 16;
      int row = o_ >> 8, colb = o_ & 255;
      int sc_ = colb ^ ((row & 7) << 4);
      __builtin_amdgcn_global_load_lds(
          (gas_cvp)(Kp + (size_t)(kk0 + row) * DMODEL + (sc_ >> 1)),
          (las_vp)(lds + bsel * 32768 + wave * 2048 + i * 1024), 16, 0, 0);
    }
#pragma unroll
    for (int i = 0; i < 2; i++) {             // V^T tile [128][64] bf16, 16KB
      int o_ = wave * 2048 + i * 1024 + lane * 16;
      int row = o_ >> 7, colb = o_ & 127;
      int sc_ = colb ^ ((row & 7) << 4);
      __builtin_amdgcn_global_load_lds(
          (gas_cvp)(Vp + (size_t)row * S_LEN + kk0 + (sc_ >> 1)),
          (las_vp)(lds + bsel * 32768 + 16384 + wave * 2048 + i * 1024), 16, 0, 0);
    }
  };

  STAGE(0, 0);
  __syncthreads();

  for (int t = 0; t < nt; t++) {
    int cur = t & 1;
    int k0 = t * 64;
    if (t + 1 < nt) STAGE(t + 1, cur ^ 1);

    bool active = (k0 <= qw + 31);
    if (active) {
      const char* kbb = lds + cur * 32768;
      f32x4 sf[2][4] = {};
#pragma unroll
      for (int kf = 0; kf < 4; kf++) {
        bf16x8 kbf[4];
#pragma unroll
        for (int nf = 0; nf < 4; nf++) {
          int row = nf * 16 + lr;
          int colb = kf * 64 + lq * 16;
          kbf[nf] = *(const bf16x8*)(kbb + row * 256 + (colb ^ ((row & 7) << 4)));
        }
#pragma unroll
        for (int nf = 0; nf < 4; nf++)
#pragma unroll
          for (int mi = 0; mi < 2; mi++)
            sf[mi][nf] = __builtin_amdgcn_mfma_f32_16x16x32_bf16(qa[mi][kf], kbf[nf], sf[mi][nf], 0, 0, 0);
      }

      float p[2][4][4];
      bool needmask = (k0 + 63 > qw);
#pragma unroll
      for (int mi = 0; mi < 2; mi++)
#pragma unroll
        for (int i2 = 0; i2 < 4; i2++) {
          int row = qw + mi * 16 + lq * 4 + i2;
          if (needmask) {
#pragma unroll
            for (int nf = 0; nf < 4; nf++) {
              int col = k0 + nf * 16 + lr;
              if (col > row) sf[mi][nf][i2] = -1e30f;
            }
          }
          float v = fmaxf(fmaxf(sf[mi][0][i2], sf[mi][1][i2]),
                          fmaxf(sf[mi][2][i2], sf[mi][3][i2]));
#pragma unroll
          for (int off = 1; off < 16; off <<= 1)
            v = fmaxf(v, __shfl_xor(v, off));
          float mn = fmaxf(mrow[mi][i2], v);
          float al = __expf(mrow[mi][i2] - mn);
          mrow[mi][i2] = mn;
          float r = 0.f;
#pragma unroll
          for (int nf = 0; nf < 4; nf++) {
            p[mi][nf][i2] = __expf(sf[mi][nf][i2] - mn);
            r += p[mi][nf][i2];
          }
#pragma unroll
          for (int off = 1; off < 16; off <<= 1)
            r += __shfl_xor(r, off);
          lsum[mi][i2] = lsum[mi][i2] * al + r;
#pragma unroll
          for (int ff = 0; ff < 8; ff++)
            o[mi][ff][i2] *= al;
        }

      // P through private per-wave LDS region (no cross-wave dep, no extra barrier)
      char* pb = lds + 65536 + wave * 4096;   // [32][64] bf16
#pragma unroll
      for (int mi = 0; mi < 2; mi++)
#pragma unroll
        for (int nf = 0; nf < 4; nf++)
#pragma unroll
          for (int i2 = 0; i2 < 4; i2++) {
            int row = mi * 16 + lq * 4 + i2;
            int colb = (nf * 16 + lr) * 2;
            *(unsigned short*)(pb + row * 128 + (colb ^ ((row & 7) << 4))) = f2bf(p[mi][nf][i2]);
          }
      asm volatile("s_waitcnt lgkmcnt(0)" ::: "memory");
      __builtin_amdgcn_sched_barrier(0);

      const char* vbb = lds + cur * 32768 + 16384;
#pragma unroll
      for (int kk = 0; kk < 2; kk++) {
        bf16x8 pa[2];
#pragma unroll
        for (int mi = 0; mi < 2; mi++) {
          int row = mi * 16 + lr;
          int colb = kk * 64 + lq * 16;
          pa[mi] = *(const bf16x8*)(pb + row * 128 + (colb ^ ((row & 7) << 4)));
        }
#pragma unroll
        for (int ff = 0; ff < 8; ff++) {
          int row = ff * 16 + lr;
          int colb = kk * 64 + lq * 16;
          bf16x8 vb = *(const bf16x8*)(vbb + row * 128 + (colb ^ ((row & 7) << 4)));
#pragma unroll
          for (int mi = 0; mi < 2; mi++)
            o[mi][ff] = __builtin_amdgcn_mfma_f32_16x16x32_bf16(pa[mi], vb, o[mi][ff], 0, 0, 0);
        }
      }
    }

    __syncthreads();   // protects buf[cur] against next iteration's STAGE
  }

#pragma unroll
  for (int mi = 0; mi < 2; mi++)
#pragma unroll
    for (int i2 = 0; i2 < 4; i2++) {
      float inv = 1.0f / lsum[mi][i2];
      size_t rb = ((size_t)b * S_LEN + qw + mi * 16 + lq * 4 + i2) * DMODEL + h * HDIM;
#pragma unroll
      for (int ff = 0; ff < 8; ff++)
        ctx[rb + ff * 16 + lr] = f2bf(o[mi][ff][i2] * inv);
    }
}

extern "C" void kernel_launch(void* const* d_in, const int* in_sizes, int n_in,
                              void* d_out, int out_size, void* d_ws, size_t ws_size,
                              hipStream_t stream) {
  const float* inq  = (const float*)d_in[0];
  const float* inkv = (const float*)d_in[1];
  const float* wq   = (const float*)d_in[2];
  const float* wk   = (const float*)d_in[3];
  const float* wv   = (const float*)d_in[4];
  const float* wo   = (const float*)d_in[5];
  float* out = (float*)d_out;

  char* ws = (char*)d_ws;
  const size_t MB = 1ull << 20;
  unsigned short* xq  = (unsigned short*)(ws);             // 16 MB (reused as Qb)
  unsigned short* xkv = (unsigned short*)(ws + 16 * MB);   // 16 MB (reused as Kb)
  unsigned short* wqt = (unsigned short*)(ws + 32 * MB);   // 8 MB
  unsigned short* wkt = (unsigned short*)(ws + 40 * MB);   // 8 MB  (wqt/wkt/wvt contiguous)
  unsigned short* wvt = (unsigned short*)(ws + 48 * MB);   // 8 MB
  unsigned short* wot = (unsigned short*)(ws + 56 * MB);   // 8 MB
  float2* sc          = (float2*)(ws + 64 * MB);           // 1 MB
  unsigned short* projb = (unsigned short*)(ws + 66 * MB); // 48 MB (Q,K,V bf16)
  unsigned short* Vt   = (unsigned short*)(ws + 114 * MB); // 16 MB
  unsigned short* ctxb = (unsigned short*)(ws + 130 * MB); // 16 MB
  unsigned short* Qb = xq;    // xq dead after proj GEMM
  unsigned short* Kb = xkv;   // xkv dead after proj GEMM

  const int n4 = (2 * S_LEN * DMODEL) / 4;
  cvt_kernel<<<n4 / 256, 256, 0, stream>>>((const float4*)inq, (ushort4*)xq, n4);
  cvt_kernel<<<n4 / 256, 256, 0, stream>>>((const float4*)inkv, (ushort4*)xkv, n4);

  dim3 tg(32, 32);
  wtrans_kernel<<<tg, 256, 0, stream>>>(wq, wqt);
  wtrans_kernel<<<tg, 256, 0, stream>>>(wk, wkt);
  wtrans_kernel<<<tg, 256, 0, stream>>>(wv, wvt);
  wtrans_kernel<<<tg, 256, 0, stream>>>(wo, wot);

  sincos_kernel<<<(S_LEN * 64) / 256, 256, 0, stream>>>(sc);

  const float qscale = 0.08838834764831845f;  // 1/sqrt(128)
  unsigned short* projQ = projb;
  unsigned short* projK = projb + (size_t)4096 * 2048;
  unsigned short* projV = projb + (size_t)2 * 4096 * 2048;

  // all three projections in one dispatch (z = op)
  gemm8_kernel<true><<<dim3(8, 16, 3), 512, 0, stream>>>(xq, xkv, wqt, (void*)projb);

  rope_kernel<<<16384, 256, 0, stream>>>(projQ, sc, Qb, qscale);
  rope_kernel<<<16384, 256, 0, stream>>>(projK, sc, Kb, 1.0f);
  vtrans_kernel<<<dim3(2, 32, 32), 256, 0, stream>>>(projV, Vt);

  attn_kernel<<<dim3(8, NH, 2), 512, 0, stream>>>(Qb, Kb, Vt, ctxb);

  gemm8_kernel<false><<<dim3(8, 16, 1), 512, 0, stream>>>(ctxb, ctxb, wot, (void*)out);
}

// Round 4
// 299.826 us; speedup vs baseline: 2.8233x; 1.2651x over previous
//
#include <hip/hip_runtime.h>

#define S_LEN 2048
#define NH 16
#define HDIM 128
#define DMODEL 2048

typedef __attribute__((ext_vector_type(8))) short bf16x8;
typedef __attribute__((ext_vector_type(4))) float f32x4;

using gas_cvp = const __attribute__((address_space(1))) void*;
using las_vp  = __attribute__((address_space(3))) void*;

__device__ __forceinline__ unsigned short f2bf(float x) {
  unsigned int u = __builtin_bit_cast(unsigned int, x);
  u += 0x7FFFu + ((u >> 16) & 1u);
  return (unsigned short)(u >> 16);
}
__device__ __forceinline__ float bf2f(unsigned short u) {
  unsigned int x = ((unsigned int)u) << 16;
  return __builtin_bit_cast(float, x);
}
__device__ __forceinline__ unsigned int cvt_pk_bf16(float lo, float hi) {
  unsigned int r;
  asm("v_cvt_pk_bf16_f32 %0, %1, %2" : "=v"(r) : "v"(lo), "v"(hi));
  return r;
}

// ---------- fp32 -> bf16 convert ----------
__global__ __launch_bounds__(256) void cvt_kernel(const float4* __restrict__ in,
                                                  ushort4* __restrict__ out, int n4) {
  int i = blockIdx.x * 256 + threadIdx.x;
  if (i < n4) {
    float4 v = in[i];
    ushort4 r;
    r.x = f2bf(v.x); r.y = f2bf(v.y); r.z = f2bf(v.z); r.w = f2bf(v.w);
    out[i] = r;
  }
}

// ---------- sin/cos table ----------
__global__ __launch_bounds__(256) void sincos_kernel(float2* __restrict__ sc) {
  int i = blockIdx.x * 256 + threadIdx.x;
  int s = i >> 6, j = i & 63;
  float inv_ts = 1.0f / powf(10000.0f, (float)j * (1.0f / 64.0f));
  float ang = (float)s * inv_ts;
  sc[i] = make_float2(sinf(ang), cosf(ang));
}

// ---------- RoPE (+scale), vectorized: 8 (x1,x2) pairs per thread ----------
__global__ __launch_bounds__(256) void rope8_kernel(const unsigned short* __restrict__ X,
                                                    const float2* __restrict__ sc,
                                                    unsigned short* __restrict__ out,
                                                    float scale) {
  int i = blockIdx.x * 256 + threadIdx.x;   // [4096][16][8]
  int m = i >> 7;
  int r = i & 127;
  int h = r >> 3, jb = (r & 7) * 8;
  int s = m & (S_LEN - 1);
  size_t base = (size_t)m * DMODEL + h * HDIM + jb;
  int4 x1 = *(const int4*)(X + base);
  int4 x2 = *(const int4*)(X + base + 64);
  const float2* pp = sc + s * 64 + jb;
  int4 o1, o2;
  int* x1w = (int*)&x1; int* x2w = (int*)&x2;
  int* o1w = (int*)&o1; int* o2w = (int*)&o2;
#pragma unroll
  for (int w = 0; w < 4; w++) {
    float a_lo = bf2f((unsigned short)(x1w[w] & 0xffff));
    float a_hi = bf2f((unsigned short)((unsigned int)x1w[w] >> 16));
    float b_lo = bf2f((unsigned short)(x2w[w] & 0xffff));
    float b_hi = bf2f((unsigned short)((unsigned int)x2w[w] >> 16));
    float2 c0 = pp[w * 2], c1 = pp[w * 2 + 1];
    float r1l = (a_lo * c0.y - b_lo * c0.x) * scale;
    float r1h = (a_hi * c1.y - b_hi * c1.x) * scale;
    float r2l = (b_lo * c0.y + a_lo * c0.x) * scale;
    float r2h = (b_hi * c1.y + a_hi * c1.x) * scale;
    o1w[w] = (int)(cvt_pk_bf16(r1l, r1h));
    o2w[w] = (int)(cvt_pk_bf16(r2l, r2h));
  }
  *(int4*)(out + base) = o1;
  *(int4*)(out + base + 64) = o2;
}

// ---------- 2048x2048 weight transpose + convert (fp32 in, bf16 out) ----------
__global__ __launch_bounds__(256) void wtrans_kernel(const float* __restrict__ in,
                                                     unsigned short* __restrict__ out) {
  __shared__ float tile[64][65];
  int c0 = blockIdx.x * 64, r0 = blockIdx.y * 64;
  int tx = threadIdx.x & 63, ty = threadIdx.x >> 6;
#pragma unroll
  for (int i = 0; i < 16; i++) {
    int r = ty + i * 4;
    tile[r][tx] = in[(size_t)(r0 + r) * DMODEL + c0 + tx];
  }
  __syncthreads();
#pragma unroll
  for (int i = 0; i < 16; i++) {
    int c = ty + i * 4;
    out[(size_t)(c0 + c) * DMODEL + r0 + tx] = f2bf(tile[tx][c]);
  }
}

// ---------- V transpose: [B,S,H,HD] bf16 -> [B,H,HD,S] bf16 ----------
__global__ __launch_bounds__(256) void vtrans_kernel(const unsigned short* __restrict__ vf,
                                                     unsigned short* __restrict__ Vt) {
  __shared__ unsigned short tile[64][65];
  int z = blockIdx.z; int b = z >> 4, h = z & 15;
  const unsigned short* I = vf + (size_t)b * S_LEN * DMODEL + h * HDIM;
  unsigned short* O = Vt + (size_t)z * HDIM * S_LEN;
  int s0 = blockIdx.y * 64, f0 = blockIdx.x * 64;
  int tx = threadIdx.x & 63, ty = threadIdx.x >> 6;
#pragma unroll
  for (int i = 0; i < 16; i++) {
    int r = ty + i * 4;
    tile[r][tx] = I[(size_t)(s0 + r) * DMODEL + f0 + tx];
  }
  __syncthreads();
#pragma unroll
  for (int i = 0; i < 16; i++) {
    int c = ty + i * 4;
    O[(size_t)(f0 + c) * S_LEN + s0 + tx] = tile[tx][c];
  }
}

// ---------- 4-phase 256x128 bf16 GEMM ----------
// C[m][n] = sum_k A[m][k]*Bt[n][k].  M=4096, N=2048, K=2048.
// 512 thr (8 waves 4Mx2N, wave tile 64x64), BK=64.
// LDS/buf 48KB: A0[128][64] | A1[128][64] | B[128][64]; dbuf 96KB.
// Stage schedule: ph1: T1.B,T1.A0; ph2: T1.A1,T+2.B, vmcnt(2); ph3: T+2.A0,A1; ph4: vmcnt(0).
template <bool BF16OUT>
__global__ __launch_bounds__(512) void gemm4_kernel(
    const unsigned short* __restrict__ Aq,
    const unsigned short* __restrict__ Akv,
    const unsigned short* __restrict__ W,   // [z][N][K]
    void* __restrict__ Cb) {                // [z][M][N]
  constexpr int M = 4096, N = 2048, K = 2048, NT = K / 64;
  __shared__ char lds[98304];
  int z = blockIdx.z;
  const unsigned short* A = (z == 0) ? Aq : Akv;
  const unsigned short* Bt = W + (size_t)z * N * K;
  int bm = blockIdx.y * 256, bn = blockIdx.x * 128;
  int tid = threadIdx.x, wave = tid >> 6, lane = tid & 63;
  int lr = lane & 15, lq = lane >> 4;
  int wr = wave >> 1, wc = wave & 1;

  // 16KB stage unit: which 0=A rows0-127, 1=A rows128-255, 2=B
  auto STAGE_U = [&](int t, int buf, int which) {
    int k0 = (t & (NT - 1)) * 64;
    const unsigned short* src = (which < 2) ? A : Bt;
    int rbase = (which < 2) ? (bm + which * 128) : bn;
    char* dst0 = lds + buf * 49152 + which * 16384;
#pragma unroll
    for (int i = 0; i < 2; i++) {
      int o = i * 8192 + wave * 1024 + lane * 16;
      int row = o >> 7, colb = o & 127;
      int sc = colb ^ ((row & 7) << 4);
      __builtin_amdgcn_global_load_lds(
          (gas_cvp)(src + (size_t)(rbase + row) * K + k0 + (sc >> 1)),
          (las_vp)(dst0 + i * 8192 + wave * 1024), 16, 0, 0);
    }
  };
  auto LDA = [&](int buf, int m, int kk) -> bf16x8 {
    int row = wr * 64 + m * 16 + lr;
    int half = row >> 7, r = row & 127;
    int byt = r * 128 + (((kk * 4 + lq) ^ (r & 7)) << 4);
    return *(const bf16x8*)(lds + buf * 49152 + half * 16384 + byt);
  };
  auto LDB = [&](int buf, int n, int kk) -> bf16x8 {
    int row = wc * 64 + n * 16 + lr;
    int byt = row * 128 + (((kk * 4 + lq) ^ (row & 7)) << 4);
    return *(const bf16x8*)(lds + buf * 49152 + 32768 + byt);
  };

  f32x4 acc[4][4] = {};
  bf16x8 aA[2][2], bB[4][2];

  auto MFMA_H = [&](int mg) {
#pragma unroll
    for (int kk = 0; kk < 2; kk++)
#pragma unroll
      for (int mm = 0; mm < 2; mm++)
#pragma unroll
        for (int nn = 0; nn < 4; nn++)
          acc[mg * 2 + mm][nn] = __builtin_amdgcn_mfma_f32_16x16x32_bf16(
              aA[mm][kk], bB[nn][kk], acc[mg * 2 + mm][nn], 0, 0, 0);
  };
  auto PHASE_SYNC = [&]() {
    __builtin_amdgcn_s_barrier();
    asm volatile("s_waitcnt lgkmcnt(0)" ::: "memory");
    __builtin_amdgcn_sched_barrier(0);
    __builtin_amdgcn_s_setprio(1);
  };
  auto PHASE_END = [&]() {
    __builtin_amdgcn_s_setprio(0);
    __builtin_amdgcn_s_barrier();
  };

  STAGE_U(0, 0, 0); STAGE_U(0, 0, 1); STAGE_U(0, 0, 2);
  asm volatile("s_waitcnt vmcnt(0)" ::: "memory");
  __builtin_amdgcn_sched_barrier(0);
  __builtin_amdgcn_s_barrier();

  for (int i = 0; i < NT / 2; i++) {
    int T1 = 2 * i + 1, TN = 2 * i + 2;
    // ph1: T0 m0,m1 x all n
#pragma unroll
    for (int kk = 0; kk < 2; kk++) {
#pragma unroll
      for (int mm = 0; mm < 2; mm++) aA[mm][kk] = LDA(0, mm, kk);
#pragma unroll
      for (int nn = 0; nn < 4; nn++) bB[nn][kk] = LDB(0, nn, kk);
    }
    STAGE_U(T1, 1, 2); STAGE_U(T1, 1, 0);
    PHASE_SYNC(); MFMA_H(0); PHASE_END();

    // ph2: T0 m2,m3
#pragma unroll
    for (int kk = 0; kk < 2; kk++)
#pragma unroll
      for (int mm = 0; mm < 2; mm++) aA[mm][kk] = LDA(0, 2 + mm, kk);
    STAGE_U(T1, 1, 1); STAGE_U(TN, 0, 2);
    asm volatile("s_waitcnt vmcnt(2)" ::: "memory");
    __builtin_amdgcn_sched_barrier(0);
    PHASE_SYNC(); MFMA_H(1); PHASE_END();

    // ph3: T1 m0,m1 x all n
#pragma unroll
    for (int kk = 0; kk < 2; kk++) {
#pragma unroll
      for (int mm = 0; mm < 2; mm++) aA[mm][kk] = LDA(1, mm, kk);
#pragma unroll
      for (int nn = 0; nn < 4; nn++) bB[nn][kk] = LDB(1, nn, kk);
    }
    STAGE_U(TN, 0, 0); STAGE_U(TN, 0, 1);
    PHASE_SYNC(); MFMA_H(0); PHASE_END();

    // ph4: T1 m2,m3
#pragma unroll
    for (int kk = 0; kk < 2; kk++)
#pragma unroll
      for (int mm = 0; mm < 2; mm++) aA[mm][kk] = LDA(1, 2 + mm, kk);
    asm volatile("s_waitcnt vmcnt(0)" ::: "memory");
    __builtin_amdgcn_sched_barrier(0);
    PHASE_SYNC(); MFMA_H(1); PHASE_END();
  }

  // epilogue
#pragma unroll
  for (int m = 0; m < 4; m++)
#pragma unroll
    for (int n = 0; n < 4; n++) {
      int row0 = bm + wr * 64 + m * 16 + lq * 4;
      int col = bn + wc * 64 + n * 16 + lr;
      if (BF16OUT) {
        unsigned short* C = (unsigned short*)Cb + (size_t)z * M * N;
#pragma unroll
        for (int r = 0; r < 4; r++)
          C[(size_t)(row0 + r) * N + col] = f2bf(acc[m][n][r]);
      } else {
        float* C = (float*)Cb + (size_t)z * M * N;
#pragma unroll
        for (int r = 0; r < 4; r++)
          C[(size_t)(row0 + r) * N + col] = acc[m][n][r];
      }
    }
}

// ---------- causal flash attention, swapped-QK^T in-register softmax ----------
// grid (8, H, B); 512 thr. Waves 0-3: q-tile jlo, waves 4-7: q-tile 15-jlo.
// S^T = mfma(K,Q): lane holds P[k-local][q], q = lane&15 (+mi*16).
// Softmax in-lane + 2 shfl; P->B-frag via cvt_pk + shfl repack; no P LDS.
__global__ __launch_bounds__(512, 1) void attn_kernel(const unsigned short* __restrict__ Qb,
                                                      const unsigned short* __restrict__ Kb,
                                                      const unsigned short* __restrict__ Vt,
                                                      unsigned short* __restrict__ ctx) {
  __shared__ char lds[65536];   // dbuf: [2][ K 16KB | V^T 16KB ]
  int b = blockIdx.z, h = blockIdx.y;
  int tid = threadIdx.x, wave = tid >> 6, lane = tid & 63;
  int lr = lane & 15, lq = lane >> 4;
  int grp = wave >> 2, wsub = wave & 3;
  int jlo = blockIdx.x;
  int qtile = grp ? (15 - jlo) : jlo;
  int qw = qtile * 128 + wsub * 32;
  int nt = 2 * (15 - jlo) + 2;

  const unsigned short* Qp = Qb + (size_t)b * S_LEN * DMODEL + (size_t)h * HDIM;
  const unsigned short* Kp = Kb + (size_t)b * S_LEN * DMODEL + (size_t)h * HDIM;
  const unsigned short* Vp = Vt + (size_t)(b * NH + h) * HDIM * S_LEN;

  // Q fragments (B-operand: row q = lr, k at lq*8)
  bf16x8 qa[2][4];
#pragma unroll
  for (int mi = 0; mi < 2; mi++)
#pragma unroll
    for (int kf = 0; kf < 4; kf++)
      qa[mi][kf] = *(const bf16x8*)(Qp + (size_t)(qw + mi * 16 + lr) * DMODEL + kf * 32 + lq * 8);

  f32x4 o[2][8] = {};
  float mrow[2] = {-1e30f, -1e30f};
  float lsum[2] = {0.f, 0.f};

  auto STAGE = [&](int tt, int bsel) {
    int kk0 = tt * 64;
#pragma unroll
    for (int i = 0; i < 2; i++) {             // K tile [64][128] bf16, 16KB
      int o_ = wave * 2048 + i * 1024 + lane * 16;
      int row = o_ >> 8, colb = o_ & 255;
      int sc_ = colb ^ ((row & 7) << 4);
      __builtin_amdgcn_global_load_lds(
          (gas_cvp)(Kp + (size_t)(kk0 + row) * DMODEL + (sc_ >> 1)),
          (las_vp)(lds + bsel * 32768 + wave * 2048 + i * 1024), 16, 0, 0);
    }
#pragma unroll
    for (int i = 0; i < 2; i++) {             // V^T tile [128][64] bf16, 16KB
      int o_ = wave * 2048 + i * 1024 + lane * 16;
      int row = o_ >> 7, colb = o_ & 127;
      int sc_ = colb ^ ((row & 7) << 4);
      __builtin_amdgcn_global_load_lds(
          (gas_cvp)(Vp + (size_t)row * S_LEN + kk0 + (sc_ >> 1)),
          (las_vp)(lds + bsel * 32768 + 16384 + wave * 2048 + i * 1024), 16, 0, 0);
    }
  };

  STAGE(0, 0);
  __syncthreads();

  for (int t = 0; t < nt; t++) {
    int cur = t & 1;
    int k0 = t * 64;
    if (t + 1 < nt) STAGE(t + 1, cur ^ 1);

    bool active = (k0 <= qw + 31);
    if (active) {
      const char* kbb = lds + cur * 32768;
      f32x4 sf[2][4] = {};
#pragma unroll
      for (int kf = 0; kf < 4; kf++) {
        bf16x8 kbf[4];
#pragma unroll
        for (int nf = 0; nf < 4; nf++) {
          int row = nf * 16 + lr;
          int colb = kf * 64 + lq * 16;
          kbf[nf] = *(const bf16x8*)(kbb + row * 256 + (colb ^ ((row & 7) << 4)));
        }
#pragma unroll
        for (int nf = 0; nf < 4; nf++)
#pragma unroll
          for (int mi = 0; mi < 2; mi++)
            sf[mi][nf] = __builtin_amdgcn_mfma_f32_16x16x32_bf16(kbf[nf], qa[mi][kf], sf[mi][nf], 0, 0, 0);
      }

      // causal mask: k = k0 + nf*16 + lq*4 + r;  q = qw + mi*16 + lr
      if (k0 + 63 > qw) {
#pragma unroll
        for (int mi = 0; mi < 2; mi++) {
          int q = qw + mi * 16 + lr;
#pragma unroll
          for (int nf = 0; nf < 4; nf++)
#pragma unroll
            for (int r = 0; r < 4; r++)
              if (k0 + nf * 16 + lq * 4 + r > q) sf[mi][nf][r] = -1e30f;
        }
      }

      // tile max per mi (in-lane 16 + shfl 16,32)
      float vmax[2];
#pragma unroll
      for (int mi = 0; mi < 2; mi++) {
        float v = sf[mi][0][0];
#pragma unroll
        for (int nf = 0; nf < 4; nf++)
#pragma unroll
          for (int r = 0; r < 4; r++) v = fmaxf(v, sf[mi][nf][r]);
        v = fmaxf(v, __shfl_xor(v, 16));
        v = fmaxf(v, __shfl_xor(v, 32));
        vmax[mi] = v;
      }
      // defer-max: rescale only when max grew by > 8
      bool need = (vmax[0] > mrow[0] + 8.f) || (vmax[1] > mrow[1] + 8.f);
      if (__any(need)) {
#pragma unroll
        for (int mi = 0; mi < 2; mi++) {
          float mn = fmaxf(mrow[mi], vmax[mi]);
          float al = __expf(mrow[mi] - mn);
          mrow[mi] = mn;
          lsum[mi] *= al;
#pragma unroll
          for (int ff = 0; ff < 8; ff++) o[mi][ff] *= al;
        }
      }
      // p = exp(s - m), row sum
#pragma unroll
      for (int mi = 0; mi < 2; mi++) {
        float rs = 0.f;
#pragma unroll
        for (int nf = 0; nf < 4; nf++)
#pragma unroll
          for (int r = 0; r < 4; r++) {
            float p = __expf(sf[mi][nf][r] - mrow[mi]);
            sf[mi][nf][r] = p;
            rs += p;
          }
        rs += __shfl_xor(rs, 16);
        rs += __shfl_xor(rs, 32);
        lsum[mi] += rs;
      }

      // repack P (lane-local k) -> PV B-fragments, then PV
      const char* vbb = lds + cur * 32768 + 16384;
      bool hi = (lane >= 32);
      bool odd = (lq & 1);
#pragma unroll
      for (int c = 0; c < 2; c++) {
        bf16x8 pfrag[2];
#pragma unroll
        for (int mi = 0; mi < 2; mi++) {
          unsigned int A0 = cvt_pk_bf16(sf[mi][2 * c][0], sf[mi][2 * c][1]);
          unsigned int A1 = cvt_pk_bf16(sf[mi][2 * c][2], sf[mi][2 * c][3]);
          unsigned int B0 = cvt_pk_bf16(sf[mi][2 * c + 1][0], sf[mi][2 * c + 1][1]);
          unsigned int B1 = cvt_pk_bf16(sf[mi][2 * c + 1][2], sf[mi][2 * c + 1][3]);
          unsigned int sA0 = (unsigned int)__shfl_xor((int)A0, 32);
          unsigned int sA1 = (unsigned int)__shfl_xor((int)A1, 32);
          unsigned int sB0 = (unsigned int)__shfl_xor((int)B0, 32);
          unsigned int sB1 = (unsigned int)__shfl_xor((int)B1, 32);
          unsigned int Y0f = hi ? sB0 : A0, Y0s = hi ? B0 : sA0;
          unsigned int Y1f = hi ? sB1 : A1, Y1s = hi ? B1 : sA1;
          unsigned int z0 = odd ? Y0f : Y0s, z1 = odd ? Y1f : Y1s;
          unsigned int w0 = (unsigned int)__shfl_xor((int)z0, 16);
          unsigned int w1 = (unsigned int)__shfl_xor((int)z1, 16);
          int4 fr;
          fr.x = (int)(odd ? w0 : Y0f);
          fr.y = (int)(odd ? w1 : Y1f);
          fr.z = (int)(odd ? Y0s : w0);
          fr.w = (int)(odd ? Y1s : w1);
          pfrag[mi] = __builtin_bit_cast(bf16x8, fr);
        }
#pragma unroll
        for (int ff = 0; ff < 8; ff++) {
          int row = ff * 16 + lr;
          int colb = c * 64 + lq * 16;
          bf16x8 vb = *(const bf16x8*)(vbb + row * 128 + (colb ^ ((row & 7) << 4)));
#pragma unroll
          for (int mi = 0; mi < 2; mi++)
            o[mi][ff] = __builtin_amdgcn_mfma_f32_16x16x32_bf16(vb, pfrag[mi], o[mi][ff], 0, 0, 0);
        }
      }
    }

    __syncthreads();   // protects buf[cur] against next iteration's STAGE
  }

  // epilogue: O^T[d][q]: q = qw + mi*16 + lr, d = ff*16 + lq*4 + r
#pragma unroll
  for (int mi = 0; mi < 2; mi++) {
    float inv = 1.0f / lsum[mi];
    size_t rb = ((size_t)b * S_LEN + qw + mi * 16 + lr) * DMODEL + h * HDIM;
#pragma unroll
    for (int ff = 0; ff < 8; ff++) {
      unsigned int u0 = cvt_pk_bf16(o[mi][ff][0] * inv, o[mi][ff][1] * inv);
      unsigned int u1 = cvt_pk_bf16(o[mi][ff][2] * inv, o[mi][ff][3] * inv);
      *(uint2*)(ctx + rb + ff * 16 + lq * 4) = make_uint2(u0, u1);
    }
  }
}

extern "C" void kernel_launch(void* const* d_in, const int* in_sizes, int n_in,
                              void* d_out, int out_size, void* d_ws, size_t ws_size,
                              hipStream_t stream) {
  const float* inq  = (const float*)d_in[0];
  const float* inkv = (const float*)d_in[1];
  const float* wq   = (const float*)d_in[2];
  const float* wk   = (const float*)d_in[3];
  const float* wv   = (const float*)d_in[4];
  const float* wo   = (const float*)d_in[5];
  float* out = (float*)d_out;

  char* ws = (char*)d_ws;
  const size_t MB = 1ull << 20;
  unsigned short* xq  = (unsigned short*)(ws);             // 16 MB (reused as Qb)
  unsigned short* xkv = (unsigned short*)(ws + 16 * MB);   // 16 MB (reused as Kb)
  unsigned short* wqt = (unsigned short*)(ws + 32 * MB);   // 8 MB
  unsigned short* wkt = (unsigned short*)(ws + 40 * MB);   // 8 MB (wqt/wkt/wvt contiguous)
  unsigned short* wvt = (unsigned short*)(ws + 48 * MB);   // 8 MB
  unsigned short* wot = (unsigned short*)(ws + 56 * MB);   // 8 MB
  float2* sc          = (float2*)(ws + 64 * MB);           // 1 MB
  unsigned short* projb = (unsigned short*)(ws + 66 * MB); // 48 MB (Q,K,V bf16)
  unsigned short* Vt   = (unsigned short*)(ws + 114 * MB); // 16 MB
  unsigned short* ctxb = (unsigned short*)(ws + 130 * MB); // 16 MB
  unsigned short* Qb = xq;    // xq dead after proj GEMM
  unsigned short* Kb = xkv;   // xkv dead after proj GEMM

  const int n4 = (2 * S_LEN * DMODEL) / 4;
  cvt_kernel<<<n4 / 256, 256, 0, stream>>>((const float4*)inq, (ushort4*)xq, n4);
  cvt_kernel<<<n4 / 256, 256, 0, stream>>>((const float4*)inkv, (ushort4*)xkv, n4);

  dim3 tg(32, 32);
  wtrans_kernel<<<tg, 256, 0, stream>>>(wq, wqt);
  wtrans_kernel<<<tg, 256, 0, stream>>>(wk, wkt);
  wtrans_kernel<<<tg, 256, 0, stream>>>(wv, wvt);
  wtrans_kernel<<<tg, 256, 0, stream>>>(wo, wot);

  sincos_kernel<<<(S_LEN * 64) / 256, 256, 0, stream>>>(sc);

  const float qscale = 0.08838834764831845f;  // 1/sqrt(128)
  unsigned short* projQ = projb;
  unsigned short* projK = projb + (size_t)4096 * 2048;
  unsigned short* projV = projb + (size_t)2 * 4096 * 2048;

  // all three projections in one dispatch (z = op); 768 blocks = 3/CU
  gemm4_kernel<true><<<dim3(16, 16, 3), 512, 0, stream>>>(xq, xkv, wqt, (void*)projb);

  rope8_kernel<<<2048, 256, 0, stream>>>(projQ, sc, Qb, qscale);
  rope8_kernel<<<2048, 256, 0, stream>>>(projK, sc, Kb, 1.0f);
  vtrans_kernel<<<dim3(2, 32, 32), 256, 0, stream>>>(projV, Vt);

  attn_kernel<<<dim3(8, NH, 2), 512, 0, stream>>>(Qb, Kb, Vt, ctxb);

  // output projection: 256 blocks = 1/CU
  gemm4_kernel<false><<<dim3(16, 16, 1), 512, 0, stream>>>(ctxb, ctxb, wot, (void*)out);
}

// Round 5
// 297.359 us; speedup vs baseline: 2.8467x; 1.0083x over previous
//
#include <hip/hip_runtime.h>

#define S_LEN 2048
#define NH 16
#define HDIM 128
#define DMODEL 2048

typedef __attribute__((ext_vector_type(8))) short bf16x8;
typedef __attribute__((ext_vector_type(4))) float f32x4;

using gas_cvp = const __attribute__((address_space(1))) void*;
using las_vp  = __attribute__((address_space(3))) void*;

__device__ __forceinline__ unsigned short f2bf(float x) {
  unsigned int u = __builtin_bit_cast(unsigned int, x);
  u += 0x7FFFu + ((u >> 16) & 1u);
  return (unsigned short)(u >> 16);
}
__device__ __forceinline__ float bf2f(unsigned short u) {
  unsigned int x = ((unsigned int)u) << 16;
  return __builtin_bit_cast(float, x);
}
__device__ __forceinline__ unsigned int cvt_pk_bf16(float lo, float hi) {
  unsigned int r;
  asm("v_cvt_pk_bf16_f32 %0, %1, %2" : "=v"(r) : "v"(lo), "v"(hi));
  return r;
}

// ---------- fp32 -> bf16 convert ----------
__global__ __launch_bounds__(256) void cvt_kernel(const float4* __restrict__ in,
                                                  ushort4* __restrict__ out, int n4) {
  int i = blockIdx.x * 256 + threadIdx.x;
  if (i < n4) {
    float4 v = in[i];
    ushort4 r;
    r.x = f2bf(v.x); r.y = f2bf(v.y); r.z = f2bf(v.z); r.w = f2bf(v.w);
    out[i] = r;
  }
}

// ---------- sin/cos table ----------
__global__ __launch_bounds__(256) void sincos_kernel(float2* __restrict__ sc) {
  int i = blockIdx.x * 256 + threadIdx.x;
  int s = i >> 6, j = i & 63;
  float inv_ts = 1.0f / powf(10000.0f, (float)j * (1.0f / 64.0f));
  float ang = (float)s * inv_ts;
  sc[i] = make_float2(sinf(ang), cosf(ang));
}

// ---------- RoPE (+scale), vectorized ----------
__global__ __launch_bounds__(256) void rope8_kernel(const unsigned short* __restrict__ X,
                                                    const float2* __restrict__ sc,
                                                    unsigned short* __restrict__ out,
                                                    float scale) {
  int i = blockIdx.x * 256 + threadIdx.x;   // [4096][16][8]
  int m = i >> 7;
  int r = i & 127;
  int h = r >> 3, jb = (r & 7) * 8;
  int s = m & (S_LEN - 1);
  size_t base = (size_t)m * DMODEL + h * HDIM + jb;
  int4 x1 = *(const int4*)(X + base);
  int4 x2 = *(const int4*)(X + base + 64);
  const float2* pp = sc + s * 64 + jb;
  int4 o1, o2;
  int* x1w = (int*)&x1; int* x2w = (int*)&x2;
  int* o1w = (int*)&o1; int* o2w = (int*)&o2;
#pragma unroll
  for (int w = 0; w < 4; w++) {
    float a_lo = bf2f((unsigned short)(x1w[w] & 0xffff));
    float a_hi = bf2f((unsigned short)((unsigned int)x1w[w] >> 16));
    float b_lo = bf2f((unsigned short)(x2w[w] & 0xffff));
    float b_hi = bf2f((unsigned short)((unsigned int)x2w[w] >> 16));
    float2 c0 = pp[w * 2], c1 = pp[w * 2 + 1];
    float r1l = (a_lo * c0.y - b_lo * c0.x) * scale;
    float r1h = (a_hi * c1.y - b_hi * c1.x) * scale;
    float r2l = (b_lo * c0.y + a_lo * c0.x) * scale;
    float r2h = (b_hi * c1.y + a_hi * c1.x) * scale;
    o1w[w] = (int)(cvt_pk_bf16(r1l, r1h));
    o2w[w] = (int)(cvt_pk_bf16(r2l, r2h));
  }
  *(int4*)(out + base) = o1;
  *(int4*)(out + base + 64) = o2;
}

// ---------- 2048x2048 weight transpose + convert (fp32 in, bf16 out) ----------
__global__ __launch_bounds__(256) void wtrans_kernel(const float* __restrict__ in,
                                                     unsigned short* __restrict__ out) {
  __shared__ float tile[64][65];
  int c0 = blockIdx.x * 64, r0 = blockIdx.y * 64;
  int tx = threadIdx.x & 63, ty = threadIdx.x >> 6;
#pragma unroll
  for (int i = 0; i < 16; i++) {
    int r = ty + i * 4;
    tile[r][tx] = in[(size_t)(r0 + r) * DMODEL + c0 + tx];
  }
  __syncthreads();
#pragma unroll
  for (int i = 0; i < 16; i++) {
    int c = ty + i * 4;
    out[(size_t)(c0 + c) * DMODEL + r0 + tx] = f2bf(tile[tx][c]);
  }
}

// ---------- V transpose: [B,S,H,HD] bf16 -> [B,H,HD,S] bf16 ----------
__global__ __launch_bounds__(256) void vtrans_kernel(const unsigned short* __restrict__ vf,
                                                     unsigned short* __restrict__ Vt) {
  __shared__ unsigned short tile[64][65];
  int z = blockIdx.z; int b = z >> 4, h = z & 15;
  const unsigned short* I = vf + (size_t)b * S_LEN * DMODEL + h * HDIM;
  unsigned short* O = Vt + (size_t)z * HDIM * S_LEN;
  int s0 = blockIdx.y * 64, f0 = blockIdx.x * 64;
  int tx = threadIdx.x & 63, ty = threadIdx.x >> 6;
#pragma unroll
  for (int i = 0; i < 16; i++) {
    int r = ty + i * 4;
    tile[r][tx] = I[(size_t)(s0 + r) * DMODEL + f0 + tx];
  }
  __syncthreads();
#pragma unroll
  for (int i = 0; i < 16; i++) {
    int c = ty + i * 4;
    O[(size_t)(f0 + c) * S_LEN + s0 + tx] = tile[tx][c];
  }
}

// ---------- triple-buffered 256x128 bf16 GEMM, 2 phases/K-tile ----------
// C[m][n] = sum_k A[m][k]*Bt[n][k].  M=4096, N=2048, K=2048.
// 512 thr (8 waves 4Mx2N, wave tile 64x64), BK=64.
// LDS 144KB = 3 bufs x 48KB {A0[128][64] | A1[128][64] | B[128][64]}.
// Prefetch distance 2 K-tiles (4 phases); steady-state s_waitcnt vmcnt(6) only.
// XCD-swizzled block ids (256 wg per z, 32/XCD contiguous).
template <bool BF16OUT>
__global__ __launch_bounds__(512) void gemm3b_kernel(
    const unsigned short* __restrict__ Aq,
    const unsigned short* __restrict__ Akv,
    const unsigned short* __restrict__ W,   // [z][N][K]
    void* __restrict__ Cb) {                // [z][M][N]
  constexpr int M = 4096, N = 2048, K = 2048, NT = K / 64;
  __shared__ char lds[147456];
  int z = blockIdx.z;
  const unsigned short* A = (z == 0) ? Aq : Akv;
  const unsigned short* Bt = W + (size_t)z * N * K;

  // bijective XCD swizzle: nwg=256 per z, q=32 per XCD, contiguous chunks
  int wid = blockIdx.y * 16 + blockIdx.x;
  int nid = (wid & 7) * 32 + (wid >> 3);
  int bn = (nid & 15) * 128, bm = (nid >> 4) * 256;

  int tid = threadIdx.x, wave = tid >> 6, lane = tid & 63;
  int lr = lane & 15, lq = lane >> 4;
  int wr = wave >> 1, wc = wave & 1;

  // 16KB stage unit: which 0=A rows0-127, 1=A rows128-255, 2=B
  auto STAGE_U = [&](int t, int buf, int which) {
    int k0 = (t & (NT - 1)) * 64;
    const unsigned short* src = (which < 2) ? A : Bt;
    int rbase = (which < 2) ? (bm + which * 128) : bn;
    char* dst0 = lds + buf * 49152 + which * 16384;
#pragma unroll
    for (int i = 0; i < 2; i++) {
      int o = i * 8192 + wave * 1024 + lane * 16;
      int row = o >> 7, colb = o & 127;
      int sc = colb ^ ((row & 7) << 4);
      __builtin_amdgcn_global_load_lds(
          (gas_cvp)(src + (size_t)(rbase + row) * K + k0 + (sc >> 1)),
          (las_vp)(dst0 + i * 8192 + wave * 1024), 16, 0, 0);
    }
  };
  auto LDA = [&](int buf, int m, int kk) -> bf16x8 {
    int row = wr * 64 + m * 16 + lr;
    int half = row >> 7, r = row & 127;
    int byt = r * 128 + (((kk * 4 + lq) ^ (r & 7)) << 4);
    return *(const bf16x8*)(lds + buf * 49152 + half * 16384 + byt);
  };
  auto LDB = [&](int buf, int n, int kk) -> bf16x8 {
    int row = wc * 64 + n * 16 + lr;
    int byt = row * 128 + (((kk * 4 + lq) ^ (row & 7)) << 4);
    return *(const bf16x8*)(lds + buf * 49152 + 32768 + byt);
  };

  f32x4 acc[4][4] = {};
  bf16x8 aA[2][2], bB[4][2];

  auto MFMA_H = [&](int mg) {
#pragma unroll
    for (int kk = 0; kk < 2; kk++)
#pragma unroll
      for (int mm = 0; mm < 2; mm++)
#pragma unroll
        for (int nn = 0; nn < 4; nn++)
          acc[mg * 2 + mm][nn] = __builtin_amdgcn_mfma_f32_16x16x32_bf16(
              aA[mm][kk], bB[nn][kk], acc[mg * 2 + mm][nn], 0, 0, 0);
  };
  auto PHASE_SYNC = [&]() {
    __builtin_amdgcn_s_barrier();
    asm volatile("s_waitcnt lgkmcnt(0)" ::: "memory");
    __builtin_amdgcn_sched_barrier(0);
    __builtin_amdgcn_s_setprio(1);
  };
  auto PHASE_END = [&]() {
    __builtin_amdgcn_s_setprio(0);
    __builtin_amdgcn_s_barrier();
  };

  // prologue: stage T0 (buf0), T1 (buf1); wait T0 landed (6 still in flight)
  STAGE_U(0, 0, 0); STAGE_U(0, 0, 1); STAGE_U(0, 0, 2);
  STAGE_U(1, 1, 0); STAGE_U(1, 1, 1); STAGE_U(1, 1, 2);
  asm volatile("s_waitcnt vmcnt(6)" ::: "memory");
  __builtin_amdgcn_sched_barrier(0);
  __builtin_amdgcn_s_barrier();

  int cur = 0;
  for (int T = 0; T < NT; T++) {
    int t2 = (T + 2) & (NT - 1);      // wraps at the tail (harmless re-stage)
    int b2 = cur + 2; if (b2 >= 3) b2 -= 3;
    // phA: A m0,m1 + all B; stage T+2 units B, A0
#pragma unroll
    for (int kk = 0; kk < 2; kk++) {
#pragma unroll
      for (int mm = 0; mm < 2; mm++) aA[mm][kk] = LDA(cur, mm, kk);
#pragma unroll
      for (int nn = 0; nn < 4; nn++) bB[nn][kk] = LDB(cur, nn, kk);
    }
    STAGE_U(t2, b2, 2); STAGE_U(t2, b2, 0);
    PHASE_SYNC(); MFMA_H(0); PHASE_END();

    // phB: A m2,m3; stage T+2 unit A1; vmcnt(6): T+1 landed, T+2 in flight
#pragma unroll
    for (int kk = 0; kk < 2; kk++)
#pragma unroll
      for (int mm = 0; mm < 2; mm++) aA[mm][kk] = LDA(cur, 2 + mm, kk);
    STAGE_U(t2, b2, 1);
    asm volatile("s_waitcnt vmcnt(6)" ::: "memory");
    __builtin_amdgcn_sched_barrier(0);
    PHASE_SYNC(); MFMA_H(1); PHASE_END();

    cur++; if (cur == 3) cur = 0;
  }

  // epilogue
#pragma unroll
  for (int m = 0; m < 4; m++)
#pragma unroll
    for (int n = 0; n < 4; n++) {
      int row0 = bm + wr * 64 + m * 16 + lq * 4;
      int col = bn + wc * 64 + n * 16 + lr;
      if (BF16OUT) {
        unsigned short* C = (unsigned short*)Cb + (size_t)z * M * N;
#pragma unroll
        for (int r = 0; r < 4; r++)
          C[(size_t)(row0 + r) * N + col] = f2bf(acc[m][n][r]);
      } else {
        float* C = (float*)Cb + (size_t)z * M * N;
#pragma unroll
        for (int r = 0; r < 4; r++)
          C[(size_t)(row0 + r) * N + col] = acc[m][n][r];
      }
    }
}

// ---------- causal flash attention, swapped-QK^T in-register softmax ----------
// 256 blocks, 512 thr. XCD swizzle: all 8 q-blocks of one (b,h) on one XCD.
// Waves 0-3: q-tile jlo, waves 4-7: q-tile 15-jlo (load balance).
__global__ __launch_bounds__(512, 1) void attn_kernel(const unsigned short* __restrict__ Qb,
                                                      const unsigned short* __restrict__ Kb,
                                                      const unsigned short* __restrict__ Vt,
                                                      unsigned short* __restrict__ ctx) {
  __shared__ char lds[65536];   // dbuf: [2][ K 16KB | V^T 16KB ]
  // linear dispatch id -> (jlo, h, b) with same-(b,h) blocks on one XCD
  int d = blockIdx.x + 8 * (blockIdx.y + 16 * blockIdx.z);
  int jlo = (d >> 3) & 7;
  int hb = (d & 7) * 4 + (d >> 6);
  int h = hb & 15, b = hb >> 4;

  int tid = threadIdx.x, wave = tid >> 6, lane = tid & 63;
  int lr = lane & 15, lq = lane >> 4;
  int grp = wave >> 2, wsub = wave & 3;
  int qtile = grp ? (15 - jlo) : jlo;
  int qw = qtile * 128 + wsub * 32;
  int nt = 2 * (15 - jlo) + 2;

  const unsigned short* Qp = Qb + (size_t)b * S_LEN * DMODEL + (size_t)h * HDIM;
  const unsigned short* Kp = Kb + (size_t)b * S_LEN * DMODEL + (size_t)h * HDIM;
  const unsigned short* Vp = Vt + (size_t)(b * NH + h) * HDIM * S_LEN;

  bf16x8 qa[2][4];
#pragma unroll
  for (int mi = 0; mi < 2; mi++)
#pragma unroll
    for (int kf = 0; kf < 4; kf++)
      qa[mi][kf] = *(const bf16x8*)(Qp + (size_t)(qw + mi * 16 + lr) * DMODEL + kf * 32 + lq * 8);

  f32x4 o[2][8] = {};
  float mrow[2] = {-1e30f, -1e30f};
  float lsum[2] = {0.f, 0.f};

  auto STAGE = [&](int tt, int bsel) {
    int kk0 = tt * 64;
#pragma unroll
    for (int i = 0; i < 2; i++) {             // K tile [64][128] bf16, 16KB
      int o_ = wave * 2048 + i * 1024 + lane * 16;
      int row = o_ >> 8, colb = o_ & 255;
      int sc_ = colb ^ ((row & 7) << 4);
      __builtin_amdgcn_global_load_lds(
          (gas_cvp)(Kp + (size_t)(kk0 + row) * DMODEL + (sc_ >> 1)),
          (las_vp)(lds + bsel * 32768 + wave * 2048 + i * 1024), 16, 0, 0);
    }
#pragma unroll
    for (int i = 0; i < 2; i++) {             // V^T tile [128][64] bf16, 16KB
      int o_ = wave * 2048 + i * 1024 + lane * 16;
      int row = o_ >> 7, colb = o_ & 127;
      int sc_ = colb ^ ((row & 7) << 4);
      __builtin_amdgcn_global_load_lds(
          (gas_cvp)(Vp + (size_t)row * S_LEN + kk0 + (sc_ >> 1)),
          (las_vp)(lds + bsel * 32768 + 16384 + wave * 2048 + i * 1024), 16, 0, 0);
    }
  };

  STAGE(0, 0);
  __syncthreads();

  for (int t = 0; t < nt; t++) {
    int cur = t & 1;
    int k0 = t * 64;
    if (t + 1 < nt) STAGE(t + 1, cur ^ 1);

    bool active = (k0 <= qw + 31);
    if (active) {
      const char* kbb = lds + cur * 32768;
      f32x4 sf[2][4] = {};
#pragma unroll
      for (int kf = 0; kf < 4; kf++) {
        bf16x8 kbf[4];
#pragma unroll
        for (int nf = 0; nf < 4; nf++) {
          int row = nf * 16 + lr;
          int colb = kf * 64 + lq * 16;
          kbf[nf] = *(const bf16x8*)(kbb + row * 256 + (colb ^ ((row & 7) << 4)));
        }
#pragma unroll
        for (int nf = 0; nf < 4; nf++)
#pragma unroll
          for (int mi = 0; mi < 2; mi++)
            sf[mi][nf] = __builtin_amdgcn_mfma_f32_16x16x32_bf16(kbf[nf], qa[mi][kf], sf[mi][nf], 0, 0, 0);
      }

      // causal mask: k = k0 + nf*16 + lq*4 + r;  q = qw + mi*16 + lr
      if (k0 + 63 > qw) {
#pragma unroll
        for (int mi = 0; mi < 2; mi++) {
          int q = qw + mi * 16 + lr;
#pragma unroll
          for (int nf = 0; nf < 4; nf++)
#pragma unroll
            for (int r = 0; r < 4; r++)
              if (k0 + nf * 16 + lq * 4 + r > q) sf[mi][nf][r] = -1e30f;
        }
      }

      float vmax[2];
#pragma unroll
      for (int mi = 0; mi < 2; mi++) {
        float v = sf[mi][0][0];
#pragma unroll
        for (int nf = 0; nf < 4; nf++)
#pragma unroll
          for (int r = 0; r < 4; r++) v = fmaxf(v, sf[mi][nf][r]);
        v = fmaxf(v, __shfl_xor(v, 16));
        v = fmaxf(v, __shfl_xor(v, 32));
        vmax[mi] = v;
      }
      bool need = (vmax[0] > mrow[0] + 8.f) || (vmax[1] > mrow[1] + 8.f);
      if (__any(need)) {
#pragma unroll
        for (int mi = 0; mi < 2; mi++) {
          float mn = fmaxf(mrow[mi], vmax[mi]);
          float al = __expf(mrow[mi] - mn);
          mrow[mi] = mn;
          lsum[mi] *= al;
#pragma unroll
          for (int ff = 0; ff < 8; ff++) o[mi][ff] *= al;
        }
      }
#pragma unroll
      for (int mi = 0; mi < 2; mi++) {
        float rs = 0.f;
#pragma unroll
        for (int nf = 0; nf < 4; nf++)
#pragma unroll
          for (int r = 0; r < 4; r++) {
            float p = __expf(sf[mi][nf][r] - mrow[mi]);
            sf[mi][nf][r] = p;
            rs += p;
          }
        rs += __shfl_xor(rs, 16);
        rs += __shfl_xor(rs, 32);
        lsum[mi] += rs;
      }

      // repack P (lane-local k) -> PV B-fragments, then PV
      const char* vbb = lds + cur * 32768 + 16384;
      bool hi = (lane >= 32);
      bool odd = (lq & 1);
#pragma unroll
      for (int c = 0; c < 2; c++) {
        bf16x8 pfrag[2];
#pragma unroll
        for (int mi = 0; mi < 2; mi++) {
          unsigned int A0 = cvt_pk_bf16(sf[mi][2 * c][0], sf[mi][2 * c][1]);
          unsigned int A1 = cvt_pk_bf16(sf[mi][2 * c][2], sf[mi][2 * c][3]);
          unsigned int B0 = cvt_pk_bf16(sf[mi][2 * c + 1][0], sf[mi][2 * c + 1][1]);
          unsigned int B1 = cvt_pk_bf16(sf[mi][2 * c + 1][2], sf[mi][2 * c + 1][3]);
          unsigned int sA0 = (unsigned int)__shfl_xor((int)A0, 32);
          unsigned int sA1 = (unsigned int)__shfl_xor((int)A1, 32);
          unsigned int sB0 = (unsigned int)__shfl_xor((int)B0, 32);
          unsigned int sB1 = (unsigned int)__shfl_xor((int)B1, 32);
          unsigned int Y0f = hi ? sB0 : A0, Y0s = hi ? B0 : sA0;
          unsigned int Y1f = hi ? sB1 : A1, Y1s = hi ? B1 : sA1;
          unsigned int z0 = odd ? Y0f : Y0s, z1 = odd ? Y1f : Y1s;
          unsigned int w0 = (unsigned int)__shfl_xor((int)z0, 16);
          unsigned int w1 = (unsigned int)__shfl_xor((int)z1, 16);
          int4 fr;
          fr.x = (int)(odd ? w0 : Y0f);
          fr.y = (int)(odd ? w1 : Y1f);
          fr.z = (int)(odd ? Y0s : w0);
          fr.w = (int)(odd ? Y1s : w1);
          pfrag[mi] = __builtin_bit_cast(bf16x8, fr);
        }
#pragma unroll
        for (int ff = 0; ff < 8; ff++) {
          int row = ff * 16 + lr;
          int colb = c * 64 + lq * 16;
          bf16x8 vb = *(const bf16x8*)(vbb + row * 128 + (colb ^ ((row & 7) << 4)));
#pragma unroll
          for (int mi = 0; mi < 2; mi++)
            o[mi][ff] = __builtin_amdgcn_mfma_f32_16x16x32_bf16(vb, pfrag[mi], o[mi][ff], 0, 0, 0);
        }
      }
    }

    __syncthreads();
  }

  // epilogue: O^T[d][q]: q = qw + mi*16 + lr, d = ff*16 + lq*4 + r
#pragma unroll
  for (int mi = 0; mi < 2; mi++) {
    float inv = 1.0f / lsum[mi];
    size_t rb = ((size_t)b * S_LEN + qw + mi * 16 + lr) * DMODEL + h * HDIM;
#pragma unroll
    for (int ff = 0; ff < 8; ff++) {
      unsigned int u0 = cvt_pk_bf16(o[mi][ff][0] * inv, o[mi][ff][1] * inv);
      unsigned int u1 = cvt_pk_bf16(o[mi][ff][2] * inv, o[mi][ff][3] * inv);
      *(uint2*)(ctx + rb + ff * 16 + lq * 4) = make_uint2(u0, u1);
    }
  }
}

extern "C" void kernel_launch(void* const* d_in, const int* in_sizes, int n_in,
                              void* d_out, int out_size, void* d_ws, size_t ws_size,
                              hipStream_t stream) {
  const float* inq  = (const float*)d_in[0];
  const float* inkv = (const float*)d_in[1];
  const float* wq   = (const float*)d_in[2];
  const float* wk   = (const float*)d_in[3];
  const float* wv   = (const float*)d_in[4];
  const float* wo   = (const float*)d_in[5];
  float* out = (float*)d_out;

  char* ws = (char*)d_ws;
  const size_t MB = 1ull << 20;
  unsigned short* xq  = (unsigned short*)(ws);             // 16 MB (reused as Qb)
  unsigned short* xkv = (unsigned short*)(ws + 16 * MB);   // 16 MB (reused as Kb)
  unsigned short* wqt = (unsigned short*)(ws + 32 * MB);   // 8 MB
  unsigned short* wkt = (unsigned short*)(ws + 40 * MB);   // 8 MB (wqt/wkt/wvt contiguous)
  unsigned short* wvt = (unsigned short*)(ws + 48 * MB);   // 8 MB
  unsigned short* wot = (unsigned short*)(ws + 56 * MB);   // 8 MB
  float2* sc          = (float2*)(ws + 64 * MB);           // 1 MB
  unsigned short* projb = (unsigned short*)(ws + 66 * MB); // 48 MB (Q,K,V bf16)
  unsigned short* Vt   = (unsigned short*)(ws + 114 * MB); // 16 MB
  unsigned short* ctxb = (unsigned short*)(ws + 130 * MB); // 16 MB
  unsigned short* Qb = xq;    // xq dead after proj GEMM
  unsigned short* Kb = xkv;   // xkv dead after proj GEMM

  const int n4 = (2 * S_LEN * DMODEL) / 4;
  cvt_kernel<<<n4 / 256, 256, 0, stream>>>((const float4*)inq, (ushort4*)xq, n4);
  cvt_kernel<<<n4 / 256, 256, 0, stream>>>((const float4*)inkv, (ushort4*)xkv, n4);

  dim3 tg(32, 32);
  wtrans_kernel<<<tg, 256, 0, stream>>>(wq, wqt);
  wtrans_kernel<<<tg, 256, 0, stream>>>(wk, wkt);
  wtrans_kernel<<<tg, 256, 0, stream>>>(wv, wvt);
  wtrans_kernel<<<tg, 256, 0, stream>>>(wo, wot);

  sincos_kernel<<<(S_LEN * 64) / 256, 256, 0, stream>>>(sc);

  const float qscale = 0.08838834764831845f;  // 1/sqrt(128)
  unsigned short* projQ = projb;
  unsigned short* projK = projb + (size_t)4096 * 2048;
  unsigned short* projV = projb + (size_t)2 * 4096 * 2048;

  // all three projections in one dispatch (z = op); 768 blocks, 3 rounds of 1/CU
  gemm3b_kernel<true><<<dim3(16, 16, 3), 512, 0, stream>>>(xq, xkv, wqt, (void*)projb);

  rope8_kernel<<<2048, 256, 0, stream>>>(projQ, sc, Qb, qscale);
  rope8_kernel<<<2048, 256, 0, stream>>>(projK, sc, Kb, 1.0f);
  vtrans_kernel<<<dim3(2, 32, 32), 256, 0, stream>>>(projV, Vt);

  attn_kernel<<<dim3(8, NH, 2), 512, 0, stream>>>(Qb, Kb, Vt, ctxb);

  // output projection: 256 blocks = 1/CU
  gemm3b_kernel<false><<<dim3(16, 16, 1), 512, 0, stream>>>(ctxb, ctxb, wot, (void*)out);
}